// Round 1
// baseline (1889.494 us; speedup 1.0000x reference)
//
#include <hip/hip_runtime.h>
#include <math.h>
#include <stdint.h>
#include <stddef.h>

#define BB 4
#define SS 2048
#define DD 1024
#define HH 16
#define HD 64
#define UU 38
#define BH (BB*HH)        // 64
#define NROWS (BB*SS)     // 8192
#define QSZ (BB*HH*SS*HD) // 8388608 floats per Q/K/V

// ---------------- projection GEMM: out(B,H,S,HD) = x @ W + b ----------------
__global__ __launch_bounds__(256) void gemm_proj(
    const float* __restrict__ A, const float* __restrict__ W,
    const float* __restrict__ bias, float* __restrict__ out)
{
  __shared__ float As[16][68];  // [k][m], padded
  __shared__ float Bs[16][68];  // [k][n], padded
  const int t  = threadIdx.x;
  const int m0 = blockIdx.y * 64;
  const int n0 = blockIdx.x * 64;
  const int lm = t >> 2, lk4 = (t & 3) * 4;   // A loads
  const int lk = t >> 4, ln4 = (t & 15) * 4;  // W loads
  const int tm = (t & 15) * 4, tn = (t >> 4) * 4;
  float acc[4][4] = {};
  for (int k0 = 0; k0 < DD; k0 += 16) {
    float4 av = *(const float4*)&A[(size_t)(m0 + lm) * DD + k0 + lk4];
    As[lk4 + 0][lm] = av.x;
    As[lk4 + 1][lm] = av.y;
    As[lk4 + 2][lm] = av.z;
    As[lk4 + 3][lm] = av.w;
    *(float4*)&Bs[lk][ln4] = *(const float4*)&W[(size_t)(k0 + lk) * DD + n0 + ln4];
    __syncthreads();
#pragma unroll
    for (int k = 0; k < 16; ++k) {
      float4 a = *(const float4*)&As[k][tm];
      float4 b = *(const float4*)&Bs[k][tn];
      acc[0][0] += a.x*b.x; acc[0][1] += a.x*b.y; acc[0][2] += a.x*b.z; acc[0][3] += a.x*b.w;
      acc[1][0] += a.y*b.x; acc[1][1] += a.y*b.y; acc[1][2] += a.y*b.z; acc[1][3] += a.y*b.w;
      acc[2][0] += a.z*b.x; acc[2][1] += a.z*b.y; acc[2][2] += a.z*b.z; acc[2][3] += a.z*b.w;
      acc[3][0] += a.w*b.x; acc[3][1] += a.w*b.y; acc[3][2] += a.w*b.z; acc[3][3] += a.w*b.w;
    }
    __syncthreads();
  }
#pragma unroll
  for (int i = 0; i < 4; ++i) {
    int r = m0 + tm + i;
    int b = r >> 11;        // r / S
    int s = r & (SS - 1);
#pragma unroll
    for (int j = 0; j < 4; ++j) {
      int c = n0 + tn + j;
      int h = c >> 6, hd = c & 63;
      out[(((size_t)(b * HH + h)) * SS + s) * HD + hd] = acc[i][j] + bias[c];
    }
  }
}

// ------------- per-(b,h) mean of sampled K rows and mean of V rows ----------
__global__ void means_kernel(const float* __restrict__ K, const float* __restrict__ V,
                             const int* __restrict__ sidx,
                             float* __restrict__ Kmean, float* __restrict__ Vmean)
{
  const int bh = blockIdx.x;
  const int d  = threadIdx.x; // 64 threads
  const float* Kb = K + (size_t)bh * SS * HD;
  const float* Vb = V + (size_t)bh * SS * HD;
  float ka = 0.f, va = 0.f;
  for (int u = 0; u < SS; ++u) ka += Kb[(size_t)sidx[u] * HD + d];
  for (int s = 0; s < SS; ++s) va += Vb[(size_t)s * HD + d];
  Kmean[bh * HD + d] = ka * (1.0f / SS);
  Vmean[bh * HD + d] = va * (1.0f / SS);
}

// --------- M[b,h,s] = (max_u Q·K[sidx[u]] - Q·Kmean*S/S) / 8  (fp32) --------
__global__ __launch_bounds__(256) void m_kernel(
    const float* __restrict__ Q, const float* __restrict__ K,
    const int* __restrict__ sidx, const float* __restrict__ Kmean,
    float* __restrict__ M)
{
  __shared__ float Qt[64][68];  // [k][q]
  __shared__ float Kt[64][68];  // [k][u]
  __shared__ float km[64];
  __shared__ float red[16][64];
  const int t  = threadIdx.x;
  const int bh = blockIdx.y;
  const int s0 = blockIdx.x * 64;
  const float* Qb = Q + (size_t)bh * SS * HD;
  const float* Kb = K + (size_t)bh * SS * HD;
  if (t < 64) km[t] = Kmean[bh * HD + t];
  {
    int q = t >> 2, kg = (t & 3) * 4;
#pragma unroll
    for (int i = 0; i < 4; ++i) {
      int kb = kg + i * 16;
      float4 v = *(const float4*)&Qb[(size_t)(s0 + q) * HD + kb];
      Qt[kb + 0][q] = v.x; Qt[kb + 1][q] = v.y; Qt[kb + 2][q] = v.z; Qt[kb + 3][q] = v.w;
    }
  }
  float runmax[4] = {-INFINITY, -INFINITY, -INFINITY, -INFINITY};
  const int tm = (t & 15) * 4, tn = (t >> 4) * 4;
  for (int u0 = 0; u0 < SS; u0 += 64) {
    __syncthreads(); // previous tile fully consumed (also covers Qt/km stores at u0=0)
    {
      int u = t >> 2, kg = (t & 3) * 4;
      int row = sidx[u0 + u];
#pragma unroll
      for (int i = 0; i < 4; ++i) {
        int kb = kg + i * 16;
        float4 v = *(const float4*)&Kb[(size_t)row * HD + kb];
        Kt[kb + 0][u] = v.x; Kt[kb + 1][u] = v.y; Kt[kb + 2][u] = v.z; Kt[kb + 3][u] = v.w;
      }
    }
    __syncthreads();
    float sacc[4][4] = {};
#pragma unroll 16
    for (int k = 0; k < 64; ++k) {
      float4 a = *(const float4*)&Qt[k][tm];
      float4 b = *(const float4*)&Kt[k][tn];
      sacc[0][0] += a.x*b.x; sacc[0][1] += a.x*b.y; sacc[0][2] += a.x*b.z; sacc[0][3] += a.x*b.w;
      sacc[1][0] += a.y*b.x; sacc[1][1] += a.y*b.y; sacc[1][2] += a.y*b.z; sacc[1][3] += a.y*b.w;
      sacc[2][0] += a.z*b.x; sacc[2][1] += a.z*b.y; sacc[2][2] += a.z*b.z; sacc[2][3] += a.z*b.w;
      sacc[3][0] += a.w*b.x; sacc[3][1] += a.w*b.y; sacc[3][2] += a.w*b.z; sacc[3][3] += a.w*b.w;
    }
#pragma unroll
    for (int i = 0; i < 4; ++i) {
      float mx = fmaxf(fmaxf(sacc[i][0], sacc[i][1]), fmaxf(sacc[i][2], sacc[i][3]));
      runmax[i] = fmaxf(runmax[i], mx);
    }
  }
  __syncthreads();
#pragma unroll
  for (int i = 0; i < 4; ++i) red[t >> 4][tm + i] = runmax[i];
  __syncthreads();
  if (t < 64) {
    float mx = red[0][t];
#pragma unroll
    for (int g = 1; g < 16; ++g) mx = fmaxf(mx, red[g][t]);
    float md = 0.f;
#pragma unroll 16
    for (int k = 0; k < 64; ++k) md += Qt[k][t] * km[k];
    M[(size_t)bh * SS + s0 + t] = (mx - md) * 0.125f;
  }
}

// ---------------- top-38 per (b,h), ties -> lower index (lax.top_k) ---------
__global__ __launch_bounds__(256) void topk_kernel(const float* __restrict__ M,
                                                   int* __restrict__ topi)
{
  __shared__ float vals[SS];
  __shared__ float rv[256];
  __shared__ int   ri[256];
  const int t  = threadIdx.x;
  const int bh = blockIdx.x;
  for (int s = t; s < SS; s += 256) vals[s] = M[(size_t)bh * SS + s];
  __syncthreads();
  for (int it = 0; it < UU; ++it) {
    float bv = -INFINITY; int bi = 0x7fffffff;
#pragma unroll
    for (int j = 0; j < 8; ++j) {
      int s = t + j * 256;
      float v = vals[s];
      if (v > bv || (v == bv && s < bi)) { bv = v; bi = s; }
    }
    rv[t] = bv; ri[t] = bi;
    __syncthreads();
    for (int w = 128; w > 0; w >>= 1) {
      if (t < w) {
        float ov = rv[t + w]; int oi = ri[t + w];
        if (ov > rv[t] || (ov == rv[t] && oi < ri[t])) { rv[t] = ov; ri[t] = oi; }
      }
      __syncthreads();
    }
    if (t == 0) { topi[bh * UU + it] = ri[0]; vals[ri[0]] = -INFINITY; }
    __syncthreads();
  }
}

// ------------ full attention for the 38 selected queries per head ----------
__global__ __launch_bounds__(256) void attn_kernel(
    const float* __restrict__ Q, const float* __restrict__ K, const float* __restrict__ V,
    const int* __restrict__ topi, float* __restrict__ ctx)
{
  __shared__ float qv[64];
  __shared__ float p[SS];
  __shared__ float red[256];
  const int t  = threadIdx.x;
  const int bh = blockIdx.x;
  const int u  = blockIdx.y;
  const int qidx = topi[bh * UU + u];
  const float* Kb = K + (size_t)bh * SS * HD;
  const float* Vb = V + (size_t)bh * SS * HD;
  if (t < 64) qv[t] = Q[((size_t)bh * SS + qidx) * HD + t];
  __syncthreads();
  float loc[8];
  float lmax = -INFINITY;
#pragma unroll
  for (int j = 0; j < 8; ++j) {
    int s = t + j * 256;
    float dot = 0.f;
#pragma unroll
    for (int k4 = 0; k4 < 64; k4 += 4) {
      float4 kk = *(const float4*)&Kb[(size_t)s * HD + k4];
      dot += qv[k4] * kk.x + qv[k4 + 1] * kk.y + qv[k4 + 2] * kk.z + qv[k4 + 3] * kk.w;
    }
    dot *= 0.125f;
    loc[j] = dot;
    lmax = fmaxf(lmax, dot);
  }
  red[t] = lmax; __syncthreads();
  for (int w = 128; w > 0; w >>= 1) { if (t < w) red[t] = fmaxf(red[t], red[t + w]); __syncthreads(); }
  float gmax = red[0];
  __syncthreads();
  float lsum = 0.f;
#pragma unroll
  for (int j = 0; j < 8; ++j) {
    float e = expf(loc[j] - gmax);
    p[t + j * 256] = e;
    lsum += e;
  }
  red[t] = lsum; __syncthreads();
  for (int w = 128; w > 0; w >>= 1) { if (t < w) red[t] += red[t + w]; __syncthreads(); }
  float inv = 1.f / red[0];
  __syncthreads();
  const int d = t & 63, g = t >> 6;
  float acc = 0.f;
  for (int s = g * 512; s < (g + 1) * 512; ++s) acc += p[s] * Vb[(size_t)s * HD + d];
  red[t] = acc; __syncthreads();
  if (t < 64) {
    float c = red[t] + red[t + 64] + red[t + 128] + red[t + 192];
    ctx[((size_t)bh * UU + u) * HD + t] = c * inv;
  }
}

// ---------- base[b,:] = Vmean_flat[b,:] @ Wo + bo  (one row per batch) ------
__global__ void base_kernel(const float* __restrict__ Vmean, const float* __restrict__ Wo,
                            const float* __restrict__ bo, float* __restrict__ base)
{
  const int c = blockIdx.x * 256 + threadIdx.x; // 1024 columns
  float acc[BB] = {};
  for (int k = 0; k < DD; ++k) {
    float w = Wo[(size_t)k * DD + c];
#pragma unroll
    for (int b = 0; b < BB; ++b) acc[b] += Vmean[b * DD + k] * w;
  }
#pragma unroll
  for (int b = 0; b < BB; ++b) base[b * DD + c] = acc[b] + bo[c];
}

// ------------------- fill every output row with base[b] --------------------
__global__ void fill_kernel(const float* __restrict__ base, float* __restrict__ out)
{
  size_t i = (size_t)blockIdx.x * 256 + threadIdx.x; // float4 index, 2^21 total
  float4 bv = ((const float4*)base)[(i >> 19) * 256 + (i & 255)];
  ((float4*)out)[i] = bv;
}

// -- selected rows: out[b,s,:] += (ctx - Vmean_h) @ Wo_h  (atomic across h) --
__global__ __launch_bounds__(256) void scatter_kernel(
    const float* __restrict__ ctx, const float* __restrict__ Vmean,
    const int* __restrict__ topi, const float* __restrict__ Wo,
    float* __restrict__ out)
{
  __shared__ float delta[64];
  const int t  = threadIdx.x;
  const int bh = blockIdx.x;  // 64
  const int u  = blockIdx.y;  // 38
  const int b = bh >> 4, h = bh & 15;
  const int s = topi[bh * UU + u];
  if (t < 64) delta[t] = ctx[((size_t)bh * UU + u) * HD + t] - Vmean[bh * HD + t];
  __syncthreads();
  float* orow = out + ((size_t)b * SS + s) * DD;
#pragma unroll
  for (int j = 0; j < 4; ++j) {
    int c = t + j * 256;
    float acc = 0.f;
#pragma unroll 8
    for (int d = 0; d < 64; ++d) acc += delta[d] * Wo[(size_t)(h * HD + d) * DD + c];
    atomicAdd(&orow[c], acc);
  }
}

extern "C" void kernel_launch(void* const* d_in, const int* in_sizes, int n_in,
                              void* d_out, int out_size, void* d_ws, size_t ws_size,
                              hipStream_t stream) {
  const float* x  = (const float*)d_in[0];
  const float* Wq = (const float*)d_in[1];
  const float* bq = (const float*)d_in[2];
  const float* Wk = (const float*)d_in[3];
  const float* bk = (const float*)d_in[4];
  const float* Wv = (const float*)d_in[5];
  const float* bv = (const float*)d_in[6];
  const float* Wo = (const float*)d_in[7];
  const float* bo = (const float*)d_in[8];
  const int* sidx = (const int*)d_in[9];
  float* out = (float*)d_out;

  float* f     = (float*)d_ws;
  float* Q     = f;
  float* K     = f + (size_t)QSZ;
  float* V     = f + (size_t)2 * QSZ;
  float* Kmean = f + (size_t)3 * QSZ;        // BH*64 = 4096
  float* Vmean = Kmean + BH * HD;            // 4096
  float* Mbuf  = Vmean + BH * HD;            // BH*SS = 131072
  float* base  = Mbuf + (size_t)BH * SS;     // BB*DD = 4096
  float* ctx   = base + BB * DD;             // BH*UU*HD = 155648
  int*   topi  = (int*)(ctx + (size_t)BH * UU * HD); // BH*UU ints

  dim3 gp(DD / 64, NROWS / 64); // (16, 128)
  gemm_proj<<<gp, 256, 0, stream>>>(x, Wq, bq, Q);
  gemm_proj<<<gp, 256, 0, stream>>>(x, Wk, bk, K);
  gemm_proj<<<gp, 256, 0, stream>>>(x, Wv, bv, V);
  means_kernel<<<BH, 64, 0, stream>>>(K, V, sidx, Kmean, Vmean);
  m_kernel<<<dim3(SS / 64, BH), 256, 0, stream>>>(Q, K, sidx, Kmean, Mbuf);
  topk_kernel<<<BH, 256, 0, stream>>>(Mbuf, topi);
  attn_kernel<<<dim3(BH, UU), 256, 0, stream>>>(Q, K, V, topi, ctx);
  base_kernel<<<DD / 256, 256, 0, stream>>>(Vmean, Wo, bo, base);
  fill_kernel<<<(NROWS * DD / 4) / 256, 256, 0, stream>>>(base, out);
  scatter_kernel<<<dim3(BH, UU), 256, 0, stream>>>(ctx, Vmean, topi, Wo, out);
}

// Round 2
// 1278.354 us; speedup vs baseline: 1.4781x; 1.4781x over previous
//
#include <hip/hip_runtime.h>
#include <math.h>
#include <stdint.h>
#include <stddef.h>

#define BB 4
#define SS 2048
#define DD 1024
#define HH 16
#define HD 64
#define UU 38
#define BH (BB*HH)        // 64
#define NROWS (BB*SS)     // 8192
#define QSZ (BB*HH*SS*HD) // 8388608 floats per Q/K/V
#define NSPLIT 4
#define SPLEN (SS/NSPLIT) // 512
#define QPAD 40

// ---------------- projection GEMM: out(B,H,S,HD) = x @ W + b ----------------
// 128x128 tile, BK=16, 256 threads, 8x8 microtile.
__global__ __launch_bounds__(256) void gemm_proj(
    const float* __restrict__ A, const float* __restrict__ W,
    const float* __restrict__ bias, float* __restrict__ out)
{
  __shared__ float As[16][132];  // [k][m]
  __shared__ float Bs[16][132];  // [k][n]
  const int t  = threadIdx.x;
  const int m0 = blockIdx.y * 128;
  const int n0 = blockIdx.x * 128;
  const int lm = t >> 1, lk8 = (t & 1) * 8;   // A loads: row lm, k-offsets lk8..lk8+7
  const int lk = t >> 4, ln8 = (t & 15) * 8;  // B loads: row lk, col-offsets ln8..ln8+7
  const int tm = (t & 15) * 8, tn = (t >> 4) * 8;
  float acc[8][8] = {};
  for (int k0 = 0; k0 < DD; k0 += 16) {
    float4 a0 = *(const float4*)&A[(size_t)(m0 + lm) * DD + k0 + lk8];
    float4 a1 = *(const float4*)&A[(size_t)(m0 + lm) * DD + k0 + lk8 + 4];
    As[lk8 + 0][lm] = a0.x; As[lk8 + 1][lm] = a0.y; As[lk8 + 2][lm] = a0.z; As[lk8 + 3][lm] = a0.w;
    As[lk8 + 4][lm] = a1.x; As[lk8 + 5][lm] = a1.y; As[lk8 + 6][lm] = a1.z; As[lk8 + 7][lm] = a1.w;
    *(float4*)&Bs[lk][ln8]     = *(const float4*)&W[(size_t)(k0 + lk) * DD + n0 + ln8];
    *(float4*)&Bs[lk][ln8 + 4] = *(const float4*)&W[(size_t)(k0 + lk) * DD + n0 + ln8 + 4];
    __syncthreads();
#pragma unroll
    for (int k = 0; k < 16; ++k) {
      float4 a0r = *(const float4*)&As[k][tm];
      float4 a1r = *(const float4*)&As[k][tm + 4];
      float4 b0r = *(const float4*)&Bs[k][tn];
      float4 b1r = *(const float4*)&Bs[k][tn + 4];
      float av[8] = {a0r.x, a0r.y, a0r.z, a0r.w, a1r.x, a1r.y, a1r.z, a1r.w};
      float bv[8] = {b0r.x, b0r.y, b0r.z, b0r.w, b1r.x, b1r.y, b1r.z, b1r.w};
#pragma unroll
      for (int i = 0; i < 8; ++i)
#pragma unroll
        for (int j = 0; j < 8; ++j) acc[i][j] += av[i] * bv[j];
    }
    __syncthreads();
  }
#pragma unroll
  for (int i = 0; i < 8; ++i) {
    int r = m0 + tm + i;
    int b = r >> 11;
    int s = r & (SS - 1);
#pragma unroll
    for (int j = 0; j < 8; ++j) {
      int c = n0 + tn + j;
      int h = c >> 6, hd = c & 63;
      out[(((size_t)(b * HH + h)) * SS + s) * HD + hd] = acc[i][j] + bias[c];
    }
  }
}

// ------------- per-(b,h) mean of sampled K rows and mean of V rows ----------
__global__ __launch_bounds__(256) void means_kernel(
    const float* __restrict__ K, const float* __restrict__ V,
    const int* __restrict__ sidx,
    float* __restrict__ Kmean, float* __restrict__ Vmean)
{
  __shared__ float rk[4][64], rv[4][64];
  const int bh = blockIdx.x;
  const int t = threadIdx.x;
  const int d = t & 63, p = t >> 6;
  const float* Kb = K + (size_t)bh * SS * HD;
  const float* Vb = V + (size_t)bh * SS * HD;
  float ka = 0.f, va = 0.f;
  for (int r = p * 512; r < (p + 1) * 512; ++r) {
    ka += Kb[(size_t)sidx[r] * HD + d];
    va += Vb[(size_t)r * HD + d];
  }
  rk[p][d] = ka; rv[p][d] = va;
  __syncthreads();
  if (t < 64) {
    Kmean[bh * HD + t] = (rk[0][t] + rk[1][t] + rk[2][t] + rk[3][t]) * (1.0f / SS);
    Vmean[bh * HD + t] = (rv[0][t] + rv[1][t] + rv[2][t] + rv[3][t]) * (1.0f / SS);
  }
}

// --------- M[b,h,s] = (max_u Q·K[sidx[u]] - Q·Kmean) / 8  (fp32) ------------
// 128 queries x 128 sampled keys per tile, 8x8 micro, HD staged in two halves.
__global__ __launch_bounds__(256) void m_kernel(
    const float* __restrict__ Q, const float* __restrict__ K,
    const int* __restrict__ sidx, const float* __restrict__ Kmean,
    float* __restrict__ M)
{
  __shared__ float Qt[64][132];   // [k][q]
  __shared__ float Kt[32][132];   // [k-half][u]
  __shared__ float red[16][128];
  __shared__ float km[64];
  __shared__ float mrun[128];
  const int t  = threadIdx.x;
  const int bh = blockIdx.y;
  const int s0 = blockIdx.x * 128;
  const float* Qb = Q + (size_t)bh * SS * HD;
  const float* Kb = K + (size_t)bh * SS * HD;
  if (t < 64) km[t] = Kmean[bh * HD + t];
  if (t < 128) mrun[t] = -INFINITY;
  {
    int lq = t >> 1, lk = (t & 1) * 32;
#pragma unroll
    for (int i = 0; i < 8; ++i) {
      float4 v = *(const float4*)&Qb[(size_t)(s0 + lq) * HD + lk + 4 * i];
      Qt[lk + 4*i + 0][lq] = v.x; Qt[lk + 4*i + 1][lq] = v.y;
      Qt[lk + 4*i + 2][lq] = v.z; Qt[lk + 4*i + 3][lq] = v.w;
    }
  }
  const int tm = (t & 15) * 8, tn = (t >> 4) * 8;
  const int lu = t >> 1, lko = (t & 1) * 16;
  for (int u0 = 0; u0 < SS; u0 += 128) {
    float sacc[8][8] = {};
    int krow = sidx[u0 + lu];
#pragma unroll
    for (int kh = 0; kh < 2; ++kh) {
      __syncthreads();  // Kt free (prev consumed), red free; first iter covers Qt/km/mrun
#pragma unroll
      for (int i = 0; i < 4; ++i) {
        float4 v = *(const float4*)&Kb[(size_t)krow * HD + kh * 32 + lko + 4 * i];
        Kt[lko + 4*i + 0][lu] = v.x; Kt[lko + 4*i + 1][lu] = v.y;
        Kt[lko + 4*i + 2][lu] = v.z; Kt[lko + 4*i + 3][lu] = v.w;
      }
      __syncthreads();
#pragma unroll
      for (int k = 0; k < 32; ++k) {
        float4 a0r = *(const float4*)&Qt[kh * 32 + k][tm];
        float4 a1r = *(const float4*)&Qt[kh * 32 + k][tm + 4];
        float4 b0r = *(const float4*)&Kt[k][tn];
        float4 b1r = *(const float4*)&Kt[k][tn + 4];
        float av[8] = {a0r.x, a0r.y, a0r.z, a0r.w, a1r.x, a1r.y, a1r.z, a1r.w};
        float bv[8] = {b0r.x, b0r.y, b0r.z, b0r.w, b1r.x, b1r.y, b1r.z, b1r.w};
#pragma unroll
        for (int i = 0; i < 8; ++i)
#pragma unroll
          for (int j = 0; j < 8; ++j) sacc[i][j] += av[i] * bv[j];
      }
    }
#pragma unroll
    for (int i = 0; i < 8; ++i) {
      float mx = sacc[i][0];
#pragma unroll
      for (int j = 1; j < 8; ++j) mx = fmaxf(mx, sacc[i][j]);
      red[t >> 4][tm + i] = mx;
    }
    __syncthreads();
    if (t < 128) {
      float mx = red[0][t];
#pragma unroll
      for (int g = 1; g < 16; ++g) mx = fmaxf(mx, red[g][t]);
      mrun[t] = fmaxf(mrun[t], mx);
    }
  }
  __syncthreads();
  if (t < 128) {
    float md = 0.f;
#pragma unroll 16
    for (int k = 0; k < 64; ++k) md += Qt[k][t] * km[k];
    M[(size_t)bh * SS + s0 + t] = (mrun[t] - md) * 0.125f;
  }
}

// ---------------- top-38 per (b,h), ties -> lower index (lax.top_k) ---------
__global__ __launch_bounds__(256) void topk_kernel(const float* __restrict__ M,
                                                   int* __restrict__ topi)
{
  __shared__ float vals[SS];
  __shared__ float rv[256];
  __shared__ int   ri[256];
  const int t  = threadIdx.x;
  const int bh = blockIdx.x;
  for (int s = t; s < SS; s += 256) vals[s] = M[(size_t)bh * SS + s];
  __syncthreads();
  for (int it = 0; it < UU; ++it) {
    float bv = -INFINITY; int bi = 0x7fffffff;
#pragma unroll
    for (int j = 0; j < 8; ++j) {
      int s = t + j * 256;
      float v = vals[s];
      if (v > bv || (v == bv && s < bi)) { bv = v; bi = s; }
    }
    rv[t] = bv; ri[t] = bi;
    __syncthreads();
    for (int w = 128; w > 0; w >>= 1) {
      if (t < w) {
        float ov = rv[t + w]; int oi = ri[t + w];
        if (ov > rv[t] || (ov == rv[t] && oi < ri[t])) { rv[t] = ov; ri[t] = oi; }
      }
      __syncthreads();
    }
    if (t == 0) { topi[bh * UU + it] = ri[0]; vals[ri[0]] = -INFINITY; }
    __syncthreads();
  }
}

// ---------- flash attention over selected queries, split over S -------------
// grid (BH, NSPLIT). 64-query padded tile (38 real), key tiles of 64.
// Emits unnormalized partial acc + running (m, l) per split.
__global__ __launch_bounds__(256) void attn_flash(
    const float* __restrict__ Q, const float* __restrict__ K, const float* __restrict__ V,
    const int* __restrict__ topi,
    float* __restrict__ pacc, float* __restrict__ pm, float* __restrict__ pl)
{
  __shared__ float Qt[64][68];   // [k][q]
  __shared__ float KV[64][68];   // K as [k][j], then V as [j][d]
  __shared__ float Ps[64][68];   // [j][q]
  __shared__ float redA[16][64];
  __shared__ float redB[16][64];
  __shared__ float mrow[64], lrow[64], scl[64];
  const int t  = threadIdx.x;
  const int bh = blockIdx.x;
  const int sp = blockIdx.y;
  const float* Kb = K + (size_t)bh * SS * HD;
  const float* Vb = V + (size_t)bh * SS * HD;
  if (t < 64) { mrow[t] = -INFINITY; lrow[t] = 0.f; }
  {
    int q = t >> 2, k4 = (t & 3) * 16;
    float4 z = {0.f, 0.f, 0.f, 0.f};
#pragma unroll
    for (int i = 0; i < 4; ++i) {
      float4 v = z;
      if (q < UU) {
        int qidx = topi[bh * UU + q];
        v = *(const float4*)&Q[((size_t)bh * SS + qidx) * HD + k4 + 4 * i];
      }
      Qt[k4 + 4*i + 0][q] = v.x; Qt[k4 + 4*i + 1][q] = v.y;
      Qt[k4 + 4*i + 2][q] = v.z; Qt[k4 + 4*i + 3][q] = v.w;
    }
  }
  const int q4 = (t & 15) * 4, j4g = (t >> 4) * 4, d4 = (t >> 4) * 4;
  const int lj = t >> 2, lk4 = (t & 3) * 16;
  float acc[4][4] = {};
  for (int s0 = sp * SPLEN; s0 < (sp + 1) * SPLEN; s0 += 64) {
    __syncthreads();  // R-boundary: KV/Ps/redA free; first iter covers Qt/mrow init
    // stage K tile transposed
#pragma unroll
    for (int i = 0; i < 4; ++i) {
      float4 v = *(const float4*)&Kb[(size_t)(s0 + lj) * HD + lk4 + 4 * i];
      KV[lk4 + 4*i + 0][lj] = v.x; KV[lk4 + 4*i + 1][lj] = v.y;
      KV[lk4 + 4*i + 2][lj] = v.z; KV[lk4 + 4*i + 3][lj] = v.w;
    }
    __syncthreads();
    // scores: 64q x 64j over k=64
    float sacc[4][4] = {};
#pragma unroll 16
    for (int k = 0; k < 64; ++k) {
      float4 a = *(const float4*)&Qt[k][q4];
      float4 b = *(const float4*)&KV[k][j4g];
      sacc[0][0] += a.x*b.x; sacc[0][1] += a.x*b.y; sacc[0][2] += a.x*b.z; sacc[0][3] += a.x*b.w;
      sacc[1][0] += a.y*b.x; sacc[1][1] += a.y*b.y; sacc[1][2] += a.y*b.z; sacc[1][3] += a.y*b.w;
      sacc[2][0] += a.z*b.x; sacc[2][1] += a.z*b.y; sacc[2][2] += a.z*b.z; sacc[2][3] += a.z*b.w;
      sacc[3][0] += a.w*b.x; sacc[3][1] += a.w*b.y; sacc[3][2] += a.w*b.z; sacc[3][3] += a.w*b.w;
    }
#pragma unroll
    for (int i = 0; i < 4; ++i) {
      float mx = fmaxf(fmaxf(sacc[i][0], sacc[i][1]), fmaxf(sacc[i][2], sacc[i][3]));
      redA[t >> 4][q4 + i] = mx;
    }
    __syncthreads();
    if (t < 64) {
      float mx = redA[0][t];
#pragma unroll
      for (int g = 1; g < 16; ++g) mx = fmaxf(mx, redA[g][t]);
      float mn = fmaxf(mrow[t], mx * 0.125f);
      scl[t] = __expf(mrow[t] - mn);   // exp(-inf)=0 on first tile
      mrow[t] = mn;
    }
    __syncthreads();
    // stage V (issue global loads first), then exp + Ps writes
    float4 vld[4];
#pragma unroll
    for (int i = 0; i < 4; ++i)
      vld[i] = *(const float4*)&Vb[(size_t)(s0 + lj) * HD + lk4 + 4 * i];
    float psum[4] = {};
#pragma unroll
    for (int i = 0; i < 4; ++i) {
#pragma unroll
      for (int j = 0; j < 4; ++j) {
        float e = __expf(sacc[i][j] * 0.125f - mrow[q4 + i]);
        Ps[j4g + j][q4 + i] = e;
        psum[i] += e;
      }
      redB[t >> 4][q4 + i] = psum[i];
    }
#pragma unroll
    for (int i = 0; i < 4; ++i)
      *(float4*)&KV[lj][lk4 + 4 * i] = vld[i];
    __syncthreads();
    if (t < 64) {
      float ts = redB[0][t];
#pragma unroll
      for (int g = 1; g < 16; ++g) ts += redB[g][t];
      lrow[t] = lrow[t] * scl[t] + ts;
    }
    // rescale accumulator and add P·V
#pragma unroll
    for (int i = 0; i < 4; ++i) {
      float f = scl[q4 + i];
      acc[i][0] *= f; acc[i][1] *= f; acc[i][2] *= f; acc[i][3] *= f;
    }
#pragma unroll 16
    for (int j = 0; j < 64; ++j) {
      float4 a = *(const float4*)&Ps[j][q4];
      float4 b = *(const float4*)&KV[j][d4];
      acc[0][0] += a.x*b.x; acc[0][1] += a.x*b.y; acc[0][2] += a.x*b.z; acc[0][3] += a.x*b.w;
      acc[1][0] += a.y*b.x; acc[1][1] += a.y*b.y; acc[1][2] += a.y*b.z; acc[1][3] += a.y*b.w;
      acc[2][0] += a.z*b.x; acc[2][1] += a.z*b.y; acc[2][2] += a.z*b.z; acc[2][3] += a.z*b.w;
      acc[3][0] += a.w*b.x; acc[3][1] += a.w*b.y; acc[3][2] += a.w*b.z; acc[3][3] += a.w*b.w;
    }
  }
  // write partials
  const size_t pb = ((size_t)bh * NSPLIT + sp) * QPAD;
#pragma unroll
  for (int i = 0; i < 4; ++i) {
    int q = q4 + i;
    if (q < UU) {
#pragma unroll
      for (int j = 0; j < 4; ++j)
        pacc[(pb + q) * HD + d4 + j] = acc[i][j];
    }
  }
  if (t < UU) { pm[pb + t] = mrow[t]; pl[pb + t] = lrow[t]; }
}

// combine split partials -> ctx
__global__ __launch_bounds__(256) void attn_combine(
    const float* __restrict__ pacc, const float* __restrict__ pm,
    const float* __restrict__ pl, float* __restrict__ ctx)
{
  const int t  = threadIdx.x;
  const int bh = blockIdx.x;
  const int d = t & 63, qg = t >> 6;
  for (int q = qg; q < UU; q += 4) {
    float m0 = pm[((size_t)bh * NSPLIT + 0) * QPAD + q];
    float m1 = pm[((size_t)bh * NSPLIT + 1) * QPAD + q];
    float m2 = pm[((size_t)bh * NSPLIT + 2) * QPAD + q];
    float m3 = pm[((size_t)bh * NSPLIT + 3) * QPAD + q];
    float ms = fmaxf(fmaxf(m0, m1), fmaxf(m2, m3));
    float w0 = __expf(m0 - ms), w1 = __expf(m1 - ms), w2 = __expf(m2 - ms), w3 = __expf(m3 - ms);
    float l = w0 * pl[((size_t)bh * NSPLIT + 0) * QPAD + q]
            + w1 * pl[((size_t)bh * NSPLIT + 1) * QPAD + q]
            + w2 * pl[((size_t)bh * NSPLIT + 2) * QPAD + q]
            + w3 * pl[((size_t)bh * NSPLIT + 3) * QPAD + q];
    float c = w0 * pacc[(((size_t)bh * NSPLIT + 0) * QPAD + q) * HD + d]
            + w1 * pacc[(((size_t)bh * NSPLIT + 1) * QPAD + q) * HD + d]
            + w2 * pacc[(((size_t)bh * NSPLIT + 2) * QPAD + q) * HD + d]
            + w3 * pacc[(((size_t)bh * NSPLIT + 3) * QPAD + q) * HD + d];
    ctx[((size_t)bh * UU + q) * HD + d] = c / l;
  }
}

// ---------- base[b,:] = Vmean_flat[b,:] @ Wo + bo  --------------------------
__global__ void base_kernel(const float* __restrict__ Vmean, const float* __restrict__ Wo,
                            const float* __restrict__ bo, float* __restrict__ base)
{
  const int c = blockIdx.x * 256 + threadIdx.x;
  float acc[BB] = {};
  for (int k = 0; k < DD; ++k) {
    float w = Wo[(size_t)k * DD + c];
#pragma unroll
    for (int b = 0; b < BB; ++b) acc[b] += Vmean[b * DD + k] * w;
  }
#pragma unroll
  for (int b = 0; b < BB; ++b) base[b * DD + c] = acc[b] + bo[c];
}

// ------------------- fill every output row with base[b] --------------------
__global__ void fill_kernel(const float* __restrict__ base, float* __restrict__ out)
{
  size_t i = (size_t)blockIdx.x * 256 + threadIdx.x;
  float4 bv = ((const float4*)base)[(i >> 19) * 256 + (i & 255)];
  ((float4*)out)[i] = bv;
}

// -- selected rows: out[b,s,:] += (ctx - Vmean_h) @ Wo_h  (atomic across h) --
__global__ __launch_bounds__(256) void scatter_kernel(
    const float* __restrict__ ctx, const float* __restrict__ Vmean,
    const int* __restrict__ topi, const float* __restrict__ Wo,
    float* __restrict__ out)
{
  __shared__ float delta[64];
  const int t  = threadIdx.x;
  const int bh = blockIdx.x;
  const int u  = blockIdx.y;
  const int b = bh >> 4, h = bh & 15;
  const int s = topi[bh * UU + u];
  if (t < 64) delta[t] = ctx[((size_t)bh * UU + u) * HD + t] - Vmean[bh * HD + t];
  __syncthreads();
  float* orow = out + ((size_t)b * SS + s) * DD;
#pragma unroll
  for (int j = 0; j < 4; ++j) {
    int c = t + j * 256;
    float acc = 0.f;
#pragma unroll 8
    for (int d = 0; d < 64; ++d) acc += delta[d] * Wo[(size_t)(h * HD + d) * DD + c];
    atomicAdd(&orow[c], acc);
  }
}

extern "C" void kernel_launch(void* const* d_in, const int* in_sizes, int n_in,
                              void* d_out, int out_size, void* d_ws, size_t ws_size,
                              hipStream_t stream) {
  const float* x  = (const float*)d_in[0];
  const float* Wq = (const float*)d_in[1];
  const float* bq = (const float*)d_in[2];
  const float* Wk = (const float*)d_in[3];
  const float* bk = (const float*)d_in[4];
  const float* Wv = (const float*)d_in[5];
  const float* bv = (const float*)d_in[6];
  const float* Wo = (const float*)d_in[7];
  const float* bo = (const float*)d_in[8];
  const int* sidx = (const int*)d_in[9];
  float* out = (float*)d_out;

  float* f     = (float*)d_ws;
  float* Q     = f;
  float* K     = f + (size_t)QSZ;
  float* V     = f + (size_t)2 * QSZ;
  float* Kmean = f + (size_t)3 * QSZ;
  float* Vmean = Kmean + BH * HD;
  float* Mbuf  = Vmean + BH * HD;
  float* base  = Mbuf + (size_t)BH * SS;
  float* ctx   = base + BB * DD;
  float* pacc  = ctx + (size_t)BH * UU * HD;               // BH*NSPLIT*QPAD*HD = 655360
  float* pm    = pacc + (size_t)BH * NSPLIT * QPAD * HD;   // 10240
  float* pl    = pm + (size_t)BH * NSPLIT * QPAD;          // 10240
  int*   topi  = (int*)(pl + (size_t)BH * NSPLIT * QPAD);

  dim3 gp(DD / 128, NROWS / 128); // (8, 64)
  gemm_proj<<<gp, 256, 0, stream>>>(x, Wq, bq, Q);
  gemm_proj<<<gp, 256, 0, stream>>>(x, Wk, bk, K);
  gemm_proj<<<gp, 256, 0, stream>>>(x, Wv, bv, V);
  means_kernel<<<BH, 256, 0, stream>>>(K, V, sidx, Kmean, Vmean);
  m_kernel<<<dim3(SS / 128, BH), 256, 0, stream>>>(Q, K, sidx, Kmean, Mbuf);
  topk_kernel<<<BH, 256, 0, stream>>>(Mbuf, topi);
  attn_flash<<<dim3(BH, NSPLIT), 256, 0, stream>>>(Q, K, V, topi, pacc, pm, pl);
  attn_combine<<<BH, 256, 0, stream>>>(pacc, pm, pl, ctx);
  base_kernel<<<DD / 256, 256, 0, stream>>>(Vmean, Wo, bo, base);
  fill_kernel<<<(NROWS * DD / 4) / 256, 256, 0, stream>>>(base, out);
  scatter_kernel<<<dim3(BH, UU), 256, 0, stream>>>(ctx, Vmean, topi, Wo, out);
}

// Round 3
// 534.452 us; speedup vs baseline: 3.5354x; 2.3919x over previous
//
#include <hip/hip_runtime.h>
#include <math.h>
#include <stdint.h>
#include <stddef.h>

#define BB 4
#define SS 2048
#define DD 1024
#define HH 16
#define HD 64
#define UU 38
#define BH (BB*HH)        // 64
#define NROWS (BB*SS)     // 8192
#define QSZ (BB*HH*SS*HD) // 8388608 floats per Q/K/V
#define NSPLIT 4
#define SPLEN (SS/NSPLIT) // 512
#define QPAD 40

typedef unsigned short ushortT;
typedef __attribute__((ext_vector_type(8))) short bf16x8;
typedef __attribute__((ext_vector_type(4))) float f32x4;

static __device__ __forceinline__ ushortT f2bf(float f) {
  union { float f; unsigned int u; } v; v.f = f;
  unsigned int r = v.u + 0x7fffu + ((v.u >> 16) & 1u);  // round-to-nearest-even
  return (ushortT)(r >> 16);
}
static __device__ __forceinline__ float bf2f(ushortT h) {
  union { unsigned int u; float f; } v; v.u = ((unsigned int)h) << 16; return v.f;
}

// ---- W [K][N] fp32 -> W^T hi/lo bf16 [N][K] (so GEMM B-tiles stage straight) ----
__global__ __launch_bounds__(256) void splitT_kernel(
    const float* __restrict__ W, ushortT* __restrict__ WhT, ushortT* __restrict__ WlT)
{
  __shared__ float tile[64][65];
  const int t = threadIdx.x;
  const int bk = blockIdx.y * 64, bn = blockIdx.x * 64;
  const int rr = t >> 4, c4 = (t & 15) * 4;
#pragma unroll
  for (int p = 0; p < 4; ++p) {
    int row = rr + p * 16;
    float4 v = *(const float4*)&W[(size_t)(bk + row) * DD + bn + c4];
    tile[row][c4] = v.x; tile[row][c4+1] = v.y; tile[row][c4+2] = v.z; tile[row][c4+3] = v.w;
  }
  __syncthreads();
  const int n = t & 63, ks = (t >> 6) * 16;
  union { ushortT us[16]; uint4 q[2]; } hb, lb;
#pragma unroll
  for (int j = 0; j < 16; ++j) {
    float f = tile[ks + j][n];
    ushortT h = f2bf(f);
    hb.us[j] = h;
    lb.us[j] = f2bf(f - bf2f(h));
  }
  size_t o = ((size_t)(bn + n) * DD + (size_t)(bk + ks)) >> 3;  // uint4 units (8 ushort)
  ((uint4*)WhT)[o] = hb.q[0]; ((uint4*)WhT)[o + 1] = hb.q[1];
  ((uint4*)WlT)[o] = lb.q[0]; ((uint4*)WlT)[o + 1] = lb.q[1];
}

// ---- projection GEMM via split-bf16 MFMA: out(B,H,S,HD) = x @ W + b ----
// 128x128 tile, BK=64, 4 waves (2x2), 16x16x32 MFMA, NC=4 exact / NC=3 fast.
template<int NC>
__global__ __launch_bounds__(256, 2) void gemm_mfma(
    const float* __restrict__ A, const ushortT* __restrict__ BhT,
    const ushortT* __restrict__ BlT, const float* __restrict__ bias,
    float* __restrict__ out)
{
  __shared__ ushortT Ah[128*64], Al[128*64], Bh[128*64], Bl[128*64];
  const int t = threadIdx.x;
  const int lin = blockIdx.x;                 // 512 = 64 m-tiles x 8 n-tiles
  const int swz = (lin & 7) * 64 + (lin >> 3); // XCD-contiguous chunks
  const int m0 = (swz >> 3) * 128;
  const int n0 = (swz & 7) * 128;
  const int lane = t & 63, w = t >> 6;
  const int wr = w >> 1, wc = w & 1;
  const int fr = lane & 15, fs = lane >> 4;
  f32x4 acc[4][4];
#pragma unroll
  for (int i = 0; i < 4; ++i)
#pragma unroll
    for (int j = 0; j < 4; ++j) acc[i][j] = (f32x4){0.f, 0.f, 0.f, 0.f};

  const int srow = t >> 3, sslot = t & 7;
  for (int ks = 0; ks < DD / 64; ++ks) {
    __syncthreads();
    // stage A tile (fp32 -> hi/lo), swizzled slot' = slot ^ (row&7) -> 2-way max
#pragma unroll
    for (int p = 0; p < 4; ++p) {
      int row = srow + p * 32;
      const float* src = &A[(size_t)(m0 + row) * DD + ks * 64 + sslot * 8];
      float4 v0 = *(const float4*)src;
      float4 v1 = *(const float4*)(src + 4);
      float fv[8] = {v0.x, v0.y, v0.z, v0.w, v1.x, v1.y, v1.z, v1.w};
      bf16x8 hv, lv;
#pragma unroll
      for (int j = 0; j < 8; ++j) {
        ushortT h = f2bf(fv[j]);
        hv[j] = (short)h;
        lv[j] = (short)f2bf(fv[j] - bf2f(h));
      }
      int off = row * 64 + ((sslot ^ (row & 7)) * 8);
      *(bf16x8*)&Ah[off] = hv;
      *(bf16x8*)&Al[off] = lv;
    }
    // stage B tiles (already bf16, pre-transposed)
#pragma unroll
    for (int p = 0; p < 4; ++p) {
      int row = srow + p * 32;
      size_t go = (size_t)(n0 + row) * DD + ks * 64 + sslot * 8;
      int off = row * 64 + ((sslot ^ (row & 7)) * 8);
      *(bf16x8*)&Bh[off] = *(const bf16x8*)&BhT[go];
      *(bf16x8*)&Bl[off] = *(const bf16x8*)&BlT[go];
    }
    __syncthreads();
#pragma unroll
    for (int kk = 0; kk < 2; ++kk) {
      bf16x8 ah[4], al[4], bh[4], bl[4];
#pragma unroll
      for (int i = 0; i < 4; ++i) {
        int row = wr * 64 + i * 16 + fr;
        int off = row * 64 + (((kk * 4 + fs) ^ (row & 7)) * 8);
        ah[i] = *(const bf16x8*)&Ah[off];
        al[i] = *(const bf16x8*)&Al[off];
      }
#pragma unroll
      for (int j = 0; j < 4; ++j) {
        int row = wc * 64 + j * 16 + fr;
        int off = row * 64 + (((kk * 4 + fs) ^ (row & 7)) * 8);
        bh[j] = *(const bf16x8*)&Bh[off];
        bl[j] = *(const bf16x8*)&Bl[off];
      }
#pragma unroll
      for (int i = 0; i < 4; ++i)
#pragma unroll
        for (int j = 0; j < 4; ++j) {
          acc[i][j] = __builtin_amdgcn_mfma_f32_16x16x32_bf16(ah[i], bh[j], acc[i][j], 0, 0, 0);
          acc[i][j] = __builtin_amdgcn_mfma_f32_16x16x32_bf16(ah[i], bl[j], acc[i][j], 0, 0, 0);
          acc[i][j] = __builtin_amdgcn_mfma_f32_16x16x32_bf16(al[i], bh[j], acc[i][j], 0, 0, 0);
          if (NC == 4)
            acc[i][j] = __builtin_amdgcn_mfma_f32_16x16x32_bf16(al[i], bl[j], acc[i][j], 0, 0, 0);
        }
    }
  }
  // epilogue: C/D layout col=lane&15, row=(lane>>4)*4+r (guide m89/m91)
#pragma unroll
  for (int i = 0; i < 4; ++i) {
#pragma unroll
    for (int j = 0; j < 4; ++j) {
      int c = n0 + wc * 64 + j * 16 + fr;
      float bs = bias[c];
      int h = c >> 6, hd = c & 63;
#pragma unroll
      for (int r = 0; r < 4; ++r) {
        int m = m0 + wr * 64 + i * 16 + fs * 4 + r;
        int b = m >> 11, s = m & (SS - 1);
        out[(((size_t)(b * HH + h)) * SS + s) * HD + hd] = acc[i][j][r] + bs;
      }
    }
  }
}

// ------------- per-(b,h) mean of sampled K rows and mean of V rows ----------
__global__ __launch_bounds__(256) void means_kernel(
    const float* __restrict__ K, const float* __restrict__ V,
    const int* __restrict__ sidx,
    float* __restrict__ Kmean, float* __restrict__ Vmean)
{
  __shared__ float rk[4][64], rv[4][64];
  const int bh = blockIdx.x;
  const int t = threadIdx.x;
  const int d = t & 63, p = t >> 6;
  const float* Kb = K + (size_t)bh * SS * HD;
  const float* Vb = V + (size_t)bh * SS * HD;
  float ka = 0.f, va = 0.f;
  for (int r = p * 512; r < (p + 1) * 512; ++r) {
    ka += Kb[(size_t)sidx[r] * HD + d];
    va += Vb[(size_t)r * HD + d];
  }
  rk[p][d] = ka; rv[p][d] = va;
  __syncthreads();
  if (t < 64) {
    Kmean[bh * HD + t] = (rk[0][t] + rk[1][t] + rk[2][t] + rk[3][t]) * (1.0f / SS);
    Vmean[bh * HD + t] = (rv[0][t] + rv[1][t] + rv[2][t] + rv[3][t]) * (1.0f / SS);
  }
}

// --------- M[b,h,s] = (max_u Q.K[sidx[u]] - Q.Kmean) / 8 via split-bf16 MFMA ---------
__global__ __launch_bounds__(256, 2) void m_mfma(
    const float* __restrict__ Q, const float* __restrict__ K,
    const int* __restrict__ sidx, const float* __restrict__ Kmean,
    float* __restrict__ M)
{
  __shared__ ushortT Qh[128*64], Ql[128*64], Kh[128*64], Kl[128*64];
  __shared__ float Mred[2][128];
  __shared__ float km[64];
  const int t = threadIdx.x;
  const int lin = blockIdx.x;                   // 1024 = 64 bh x 16 q-tiles
  const int swz = (lin & 7) * 128 + (lin >> 3); // XCD-contiguous: 8 bh per XCD
  const int bh = swz >> 4;
  const int s0 = (swz & 15) * 128;
  const float* Qb = Q + (size_t)bh * SS * HD;
  const float* Kb = K + (size_t)bh * SS * HD;
  const int lane = t & 63, w = t >> 6;
  const int wr = w >> 1, wc = w & 1;
  const int fr = lane & 15, fs = lane >> 4;
  if (t < 64) km[t] = Kmean[bh * HD + t];
  const int srow = t >> 3, sslot = t & 7;
  // stage Q tile once (HD=64 = whole K-dim)
#pragma unroll
  for (int p = 0; p < 4; ++p) {
    int row = srow + p * 32;
    const float* src = &Qb[(size_t)(s0 + row) * HD + sslot * 8];
    float4 v0 = *(const float4*)src;
    float4 v1 = *(const float4*)(src + 4);
    float fv[8] = {v0.x, v0.y, v0.z, v0.w, v1.x, v1.y, v1.z, v1.w};
    bf16x8 hv, lv;
#pragma unroll
    for (int j = 0; j < 8; ++j) {
      ushortT h = f2bf(fv[j]);
      hv[j] = (short)h;
      lv[j] = (short)f2bf(fv[j] - bf2f(h));
    }
    int off = row * 64 + ((sslot ^ (row & 7)) * 8);
    *(bf16x8*)&Qh[off] = hv;
    *(bf16x8*)&Ql[off] = lv;
  }
  float runmax[4][4];
#pragma unroll
  for (int i = 0; i < 4; ++i)
#pragma unroll
    for (int r = 0; r < 4; ++r) runmax[i][r] = -INFINITY;

  for (int u0 = 0; u0 < SS; u0 += 128) {
    __syncthreads();  // prev K tile consumed; 2nd barrier below covers Q staging
#pragma unroll
    for (int p = 0; p < 4; ++p) {
      int row = srow + p * 32;
      int gr = sidx[u0 + row];
      const float* src = &Kb[(size_t)gr * HD + sslot * 8];
      float4 v0 = *(const float4*)src;
      float4 v1 = *(const float4*)(src + 4);
      float fv[8] = {v0.x, v0.y, v0.z, v0.w, v1.x, v1.y, v1.z, v1.w};
      bf16x8 hv, lv;
#pragma unroll
      for (int j = 0; j < 8; ++j) {
        ushortT h = f2bf(fv[j]);
        hv[j] = (short)h;
        lv[j] = (short)f2bf(fv[j] - bf2f(h));
      }
      int off = row * 64 + ((sslot ^ (row & 7)) * 8);
      *(bf16x8*)&Kh[off] = hv;
      *(bf16x8*)&Kl[off] = lv;
    }
    __syncthreads();
    f32x4 acc[4][4];
#pragma unroll
    for (int i = 0; i < 4; ++i)
#pragma unroll
      for (int j = 0; j < 4; ++j) acc[i][j] = (f32x4){0.f, 0.f, 0.f, 0.f};
#pragma unroll
    for (int kk = 0; kk < 2; ++kk) {
      bf16x8 ah[4], al[4], bh[4], bl[4];
#pragma unroll
      for (int i = 0; i < 4; ++i) {
        int row = wr * 64 + i * 16 + fr;
        int off = row * 64 + (((kk * 4 + fs) ^ (row & 7)) * 8);
        ah[i] = *(const bf16x8*)&Qh[off];
        al[i] = *(const bf16x8*)&Ql[off];
      }
#pragma unroll
      for (int j = 0; j < 4; ++j) {
        int row = wc * 64 + j * 16 + fr;
        int off = row * 64 + (((kk * 4 + fs) ^ (row & 7)) * 8);
        bh[j] = *(const bf16x8*)&Kh[off];
        bl[j] = *(const bf16x8*)&Kl[off];
      }
#pragma unroll
      for (int i = 0; i < 4; ++i)
#pragma unroll
        for (int j = 0; j < 4; ++j) {
          acc[i][j] = __builtin_amdgcn_mfma_f32_16x16x32_bf16(ah[i], bh[j], acc[i][j], 0, 0, 0);
          acc[i][j] = __builtin_amdgcn_mfma_f32_16x16x32_bf16(ah[i], bl[j], acc[i][j], 0, 0, 0);
          acc[i][j] = __builtin_amdgcn_mfma_f32_16x16x32_bf16(al[i], bh[j], acc[i][j], 0, 0, 0);
          acc[i][j] = __builtin_amdgcn_mfma_f32_16x16x32_bf16(al[i], bl[j], acc[i][j], 0, 0, 0);
        }
    }
#pragma unroll
    for (int i = 0; i < 4; ++i)
#pragma unroll
      for (int j = 0; j < 4; ++j) {
#pragma unroll
        for (int r = 0; r < 4; ++r) runmax[i][r] = fmaxf(runmax[i][r], acc[i][j][r]);
      }
  }
  // reduce over the 16 lanes (fr) holding different key-columns of the same row
#pragma unroll
  for (int i = 0; i < 4; ++i)
#pragma unroll
    for (int r = 0; r < 4; ++r) {
      float v = runmax[i][r];
      v = fmaxf(v, __shfl_xor(v, 1, 64));
      v = fmaxf(v, __shfl_xor(v, 2, 64));
      v = fmaxf(v, __shfl_xor(v, 4, 64));
      v = fmaxf(v, __shfl_xor(v, 8, 64));
      runmax[i][r] = v;
    }
  if (fr == 0) {
#pragma unroll
    for (int i = 0; i < 4; ++i)
#pragma unroll
      for (int r = 0; r < 4; ++r)
        Mred[wc][wr * 64 + i * 16 + fs * 4 + r] = runmax[i][r];
  }
  __syncthreads();
  if (t < 128) {
    float mx = fmaxf(Mred[0][t], Mred[1][t]);
    float md = 0.f;
    const float* qrow = &Qb[(size_t)(s0 + t) * HD];
#pragma unroll 16
    for (int k = 0; k < 64; ++k) md += qrow[k] * km[k];
    M[(size_t)bh * SS + s0 + t] = (mx - md) * 0.125f;
  }
}

// ---------------- top-38 per (b,h), ties -> lower index (lax.top_k) ---------
__global__ __launch_bounds__(256) void topk_kernel(const float* __restrict__ M,
                                                   int* __restrict__ topi)
{
  __shared__ float vals[SS];
  __shared__ float rv[256];
  __shared__ int   ri[256];
  const int t  = threadIdx.x;
  const int bh = blockIdx.x;
  for (int s = t; s < SS; s += 256) vals[s] = M[(size_t)bh * SS + s];
  __syncthreads();
  for (int it = 0; it < UU; ++it) {
    float bv = -INFINITY; int bi = 0x7fffffff;
#pragma unroll
    for (int j = 0; j < 8; ++j) {
      int s = t + j * 256;
      float v = vals[s];
      if (v > bv || (v == bv && s < bi)) { bv = v; bi = s; }
    }
    rv[t] = bv; ri[t] = bi;
    __syncthreads();
    for (int w = 128; w > 0; w >>= 1) {
      if (t < w) {
        float ov = rv[t + w]; int oi = ri[t + w];
        if (ov > rv[t] || (ov == rv[t] && oi < ri[t])) { rv[t] = ov; ri[t] = oi; }
      }
      __syncthreads();
    }
    if (t == 0) { topi[bh * UU + it] = ri[0]; vals[ri[0]] = -INFINITY; }
    __syncthreads();
  }
}

// ---------- flash attention over selected queries, split over S -------------
__global__ __launch_bounds__(256) void attn_flash(
    const float* __restrict__ Q, const float* __restrict__ K, const float* __restrict__ V,
    const int* __restrict__ topi,
    float* __restrict__ pacc, float* __restrict__ pm, float* __restrict__ pl)
{
  __shared__ float Qt[64][68];
  __shared__ float KV[64][68];
  __shared__ float Ps[64][68];
  __shared__ float redA[16][64];
  __shared__ float redB[16][64];
  __shared__ float mrow[64], lrow[64], scl[64];
  const int t  = threadIdx.x;
  const int bh = blockIdx.x;
  const int sp = blockIdx.y;
  const float* Kb = K + (size_t)bh * SS * HD;
  const float* Vb = V + (size_t)bh * SS * HD;
  if (t < 64) { mrow[t] = -INFINITY; lrow[t] = 0.f; }
  {
    int q = t >> 2, k4 = (t & 3) * 16;
    float4 z = {0.f, 0.f, 0.f, 0.f};
#pragma unroll
    for (int i = 0; i < 4; ++i) {
      float4 v = z;
      if (q < UU) {
        int qidx = topi[bh * UU + q];
        v = *(const float4*)&Q[((size_t)bh * SS + qidx) * HD + k4 + 4 * i];
      }
      Qt[k4 + 4*i + 0][q] = v.x; Qt[k4 + 4*i + 1][q] = v.y;
      Qt[k4 + 4*i + 2][q] = v.z; Qt[k4 + 4*i + 3][q] = v.w;
    }
  }
  const int q4 = (t & 15) * 4, j4g = (t >> 4) * 4, d4 = (t >> 4) * 4;
  const int lj = t >> 2, lk4 = (t & 3) * 16;
  float acc[4][4] = {};
  for (int s0 = sp * SPLEN; s0 < (sp + 1) * SPLEN; s0 += 64) {
    __syncthreads();
#pragma unroll
    for (int i = 0; i < 4; ++i) {
      float4 v = *(const float4*)&Kb[(size_t)(s0 + lj) * HD + lk4 + 4 * i];
      KV[lk4 + 4*i + 0][lj] = v.x; KV[lk4 + 4*i + 1][lj] = v.y;
      KV[lk4 + 4*i + 2][lj] = v.z; KV[lk4 + 4*i + 3][lj] = v.w;
    }
    __syncthreads();
    float sacc[4][4] = {};
#pragma unroll 16
    for (int k = 0; k < 64; ++k) {
      float4 a = *(const float4*)&Qt[k][q4];
      float4 b = *(const float4*)&KV[k][j4g];
      sacc[0][0] += a.x*b.x; sacc[0][1] += a.x*b.y; sacc[0][2] += a.x*b.z; sacc[0][3] += a.x*b.w;
      sacc[1][0] += a.y*b.x; sacc[1][1] += a.y*b.y; sacc[1][2] += a.y*b.z; sacc[1][3] += a.y*b.w;
      sacc[2][0] += a.z*b.x; sacc[2][1] += a.z*b.y; sacc[2][2] += a.z*b.z; sacc[2][3] += a.z*b.w;
      sacc[3][0] += a.w*b.x; sacc[3][1] += a.w*b.y; sacc[3][2] += a.w*b.z; sacc[3][3] += a.w*b.w;
    }
#pragma unroll
    for (int i = 0; i < 4; ++i) {
      float mx = fmaxf(fmaxf(sacc[i][0], sacc[i][1]), fmaxf(sacc[i][2], sacc[i][3]));
      redA[t >> 4][q4 + i] = mx;
    }
    __syncthreads();
    if (t < 64) {
      float mx = redA[0][t];
#pragma unroll
      for (int g = 1; g < 16; ++g) mx = fmaxf(mx, redA[g][t]);
      float mn = fmaxf(mrow[t], mx * 0.125f);
      scl[t] = __expf(mrow[t] - mn);
      mrow[t] = mn;
    }
    __syncthreads();
    float4 vld[4];
#pragma unroll
    for (int i = 0; i < 4; ++i)
      vld[i] = *(const float4*)&Vb[(size_t)(s0 + lj) * HD + lk4 + 4 * i];
    float psum[4] = {};
#pragma unroll
    for (int i = 0; i < 4; ++i) {
#pragma unroll
      for (int j = 0; j < 4; ++j) {
        float e = __expf(sacc[i][j] * 0.125f - mrow[q4 + i]);
        Ps[j4g + j][q4 + i] = e;
        psum[i] += e;
      }
      redB[t >> 4][q4 + i] = psum[i];
    }
#pragma unroll
    for (int i = 0; i < 4; ++i)
      *(float4*)&KV[lj][lk4 + 4 * i] = vld[i];
    __syncthreads();
    if (t < 64) {
      float ts = redB[0][t];
#pragma unroll
      for (int g = 1; g < 16; ++g) ts += redB[g][t];
      lrow[t] = lrow[t] * scl[t] + ts;
    }
#pragma unroll
    for (int i = 0; i < 4; ++i) {
      float fsc = scl[q4 + i];
      acc[i][0] *= fsc; acc[i][1] *= fsc; acc[i][2] *= fsc; acc[i][3] *= fsc;
    }
#pragma unroll 16
    for (int j = 0; j < 64; ++j) {
      float4 a = *(const float4*)&Ps[j][q4];
      float4 b = *(const float4*)&KV[j][d4];
      acc[0][0] += a.x*b.x; acc[0][1] += a.x*b.y; acc[0][2] += a.x*b.z; acc[0][3] += a.x*b.w;
      acc[1][0] += a.y*b.x; acc[1][1] += a.y*b.y; acc[1][2] += a.y*b.z; acc[1][3] += a.y*b.w;
      acc[2][0] += a.z*b.x; acc[2][1] += a.z*b.y; acc[2][2] += a.z*b.z; acc[2][3] += a.z*b.w;
      acc[3][0] += a.w*b.x; acc[3][1] += a.w*b.y; acc[3][2] += a.w*b.z; acc[3][3] += a.w*b.w;
    }
  }
  const size_t pb = ((size_t)bh * NSPLIT + sp) * QPAD;
#pragma unroll
  for (int i = 0; i < 4; ++i) {
    int q = q4 + i;
    if (q < UU) {
#pragma unroll
      for (int j = 0; j < 4; ++j)
        pacc[(pb + q) * HD + d4 + j] = acc[i][j];
    }
  }
  if (t < UU) { pm[pb + t] = mrow[t]; pl[pb + t] = lrow[t]; }
}

__global__ __launch_bounds__(256) void attn_combine(
    const float* __restrict__ pacc, const float* __restrict__ pm,
    const float* __restrict__ pl, float* __restrict__ ctx)
{
  const int t  = threadIdx.x;
  const int bh = blockIdx.x;
  const int d = t & 63, qg = t >> 6;
  for (int q = qg; q < UU; q += 4) {
    float m0 = pm[((size_t)bh * NSPLIT + 0) * QPAD + q];
    float m1 = pm[((size_t)bh * NSPLIT + 1) * QPAD + q];
    float m2 = pm[((size_t)bh * NSPLIT + 2) * QPAD + q];
    float m3 = pm[((size_t)bh * NSPLIT + 3) * QPAD + q];
    float ms = fmaxf(fmaxf(m0, m1), fmaxf(m2, m3));
    float w0 = __expf(m0 - ms), w1 = __expf(m1 - ms), w2 = __expf(m2 - ms), w3 = __expf(m3 - ms);
    float l = w0 * pl[((size_t)bh * NSPLIT + 0) * QPAD + q]
            + w1 * pl[((size_t)bh * NSPLIT + 1) * QPAD + q]
            + w2 * pl[((size_t)bh * NSPLIT + 2) * QPAD + q]
            + w3 * pl[((size_t)bh * NSPLIT + 3) * QPAD + q];
    float c = w0 * pacc[(((size_t)bh * NSPLIT + 0) * QPAD + q) * HD + d]
            + w1 * pacc[(((size_t)bh * NSPLIT + 1) * QPAD + q) * HD + d]
            + w2 * pacc[(((size_t)bh * NSPLIT + 2) * QPAD + q) * HD + d]
            + w3 * pacc[(((size_t)bh * NSPLIT + 3) * QPAD + q) * HD + d];
    ctx[((size_t)bh * UU + q) * HD + d] = c / l;
  }
}

__global__ void base_kernel(const float* __restrict__ Vmean, const float* __restrict__ Wo,
                            const float* __restrict__ bo, float* __restrict__ base)
{
  const int c = blockIdx.x * 256 + threadIdx.x;
  float acc[BB] = {};
  for (int k = 0; k < DD; ++k) {
    float w = Wo[(size_t)k * DD + c];
#pragma unroll
    for (int b = 0; b < BB; ++b) acc[b] += Vmean[b * DD + k] * w;
  }
#pragma unroll
  for (int b = 0; b < BB; ++b) base[b * DD + c] = acc[b] + bo[c];
}

__global__ void fill_kernel(const float* __restrict__ base, float* __restrict__ out)
{
  size_t i = (size_t)blockIdx.x * 256 + threadIdx.x;
  float4 bv = ((const float4*)base)[(i >> 19) * 256 + (i & 255)];
  ((float4*)out)[i] = bv;
}

__global__ __launch_bounds__(256) void scatter_kernel(
    const float* __restrict__ ctx, const float* __restrict__ Vmean,
    const int* __restrict__ topi, const float* __restrict__ Wo,
    float* __restrict__ out)
{
  __shared__ float delta[64];
  const int t  = threadIdx.x;
  const int bh = blockIdx.x;
  const int u  = blockIdx.y;
  const int b = bh >> 4, h = bh & 15;
  const int s = topi[bh * UU + u];
  if (t < 64) delta[t] = ctx[((size_t)bh * UU + u) * HD + t] - Vmean[bh * HD + t];
  __syncthreads();
  float* orow = out + ((size_t)b * SS + s) * DD;
#pragma unroll
  for (int j = 0; j < 4; ++j) {
    int c = t + j * 256;
    float acc = 0.f;
#pragma unroll 8
    for (int d = 0; d < 64; ++d) acc += delta[d] * Wo[(size_t)(h * HD + d) * DD + c];
    atomicAdd(&orow[c], acc);
  }
}

extern "C" void kernel_launch(void* const* d_in, const int* in_sizes, int n_in,
                              void* d_out, int out_size, void* d_ws, size_t ws_size,
                              hipStream_t stream) {
  const float* x  = (const float*)d_in[0];
  const float* Wq = (const float*)d_in[1];
  const float* bq = (const float*)d_in[2];
  const float* Wk = (const float*)d_in[3];
  const float* bk = (const float*)d_in[4];
  const float* Wv = (const float*)d_in[5];
  const float* bv = (const float*)d_in[6];
  const float* Wo = (const float*)d_in[7];
  const float* bo = (const float*)d_in[8];
  const int* sidx = (const int*)d_in[9];
  float* out = (float*)d_out;

  float* f     = (float*)d_ws;
  float* Q     = f;
  float* K     = f + (size_t)QSZ;
  float* V     = f + (size_t)2 * QSZ;
  float* Kmean = f + (size_t)3 * QSZ;
  float* Vmean = Kmean + BH * HD;
  float* Mbuf  = Vmean + BH * HD;
  float* base  = Mbuf + (size_t)BH * SS;
  float* ctx   = base + BB * DD;
  float* pacc  = ctx + (size_t)BH * UU * HD;
  float* pm    = pacc + (size_t)BH * NSPLIT * QPAD * HD;
  float* pl    = pm + (size_t)BH * NSPLIT * QPAD;
  int*   topi  = (int*)(pl + (size_t)BH * NSPLIT * QPAD);
  ushortT* wsp = (ushortT*)(topi + 1024);
  ushortT* WqhT = wsp;
  ushortT* WqlT = WqhT + (size_t)DD * DD;
  ushortT* WkhT = WqlT + (size_t)DD * DD;
  ushortT* WklT = WkhT + (size_t)DD * DD;
  ushortT* WvhT = WklT + (size_t)DD * DD;
  ushortT* WvlT = WvhT + (size_t)DD * DD;

  dim3 gs(16, 16);
  splitT_kernel<<<gs, 256, 0, stream>>>(Wq, WqhT, WqlT);
  splitT_kernel<<<gs, 256, 0, stream>>>(Wk, WkhT, WklT);
  splitT_kernel<<<gs, 256, 0, stream>>>(Wv, WvhT, WvlT);
  gemm_mfma<4><<<512, 256, 0, stream>>>(x, WqhT, WqlT, bq, Q);
  gemm_mfma<4><<<512, 256, 0, stream>>>(x, WkhT, WklT, bk, K);
  gemm_mfma<3><<<512, 256, 0, stream>>>(x, WvhT, WvlT, bv, V);
  means_kernel<<<BH, 256, 0, stream>>>(K, V, sidx, Kmean, Vmean);
  m_mfma<<<1024, 256, 0, stream>>>(Q, K, sidx, Kmean, Mbuf);
  topk_kernel<<<BH, 256, 0, stream>>>(Mbuf, topi);
  attn_flash<<<dim3(BH, NSPLIT), 256, 0, stream>>>(Q, K, V, topi, pacc, pm, pl);
  attn_combine<<<BH, 256, 0, stream>>>(pacc, pm, pl, ctx);
  base_kernel<<<DD / 256, 256, 0, stream>>>(Vmean, Wo, bo, base);
  fill_kernel<<<(NROWS * DD / 4) / 256, 256, 0, stream>>>(base, out);
  scatter_kernel<<<dim3(BH, UU), 256, 0, stream>>>(ctx, Vmean, topi, Wo, out);
}

// Round 4
// 493.869 us; speedup vs baseline: 3.8259x; 1.0822x over previous
//
#include <hip/hip_runtime.h>
#include <math.h>
#include <stdint.h>
#include <stddef.h>

#define BB 4
#define SS 2048
#define DD 1024
#define HH 16
#define HD 64
#define UU 38
#define BH (BB*HH)        // 64
#define NROWS (BB*SS)     // 8192
#define QSZ (BB*HH*SS*HD) // 8388608 floats per Q/K/V
#define NSPLIT 4
#define SPLEN (SS/NSPLIT) // 512
#define QPAD 40

typedef unsigned short ushortT;
typedef __attribute__((ext_vector_type(8))) short bf16x8;
typedef __attribute__((ext_vector_type(4))) float f32x4;

static __device__ __forceinline__ ushortT f2bf(float f) {
  union { float f; unsigned int u; } v; v.f = f;
  unsigned int r = v.u + 0x7fffu + ((v.u >> 16) & 1u);  // round-to-nearest-even
  return (ushortT)(r >> 16);
}
static __device__ __forceinline__ float bf2f(ushortT h) {
  union { unsigned int u; float f; } v; v.u = ((unsigned int)h) << 16; return v.f;
}

// ---- x fp32 -> xh/xl bf16 (row-major, same layout) ----
__global__ __launch_bounds__(256) void split_x(
    const float* __restrict__ x, ushortT* __restrict__ xh, ushortT* __restrict__ xl)
{
  size_t i = ((size_t)blockIdx.x * 256 + threadIdx.x) * 8;
  float4 v0 = *(const float4*)&x[i];
  float4 v1 = *(const float4*)&x[i + 4];
  float fv[8] = {v0.x, v0.y, v0.z, v0.w, v1.x, v1.y, v1.z, v1.w};
  bf16x8 hv, lv;
#pragma unroll
  for (int j = 0; j < 8; ++j) {
    ushortT h = f2bf(fv[j]);
    hv[j] = (short)h;
    lv[j] = (short)f2bf(fv[j] - bf2f(h));
  }
  *(bf16x8*)&xh[i] = hv;
  *(bf16x8*)&xl[i] = lv;
}

// ---- W [K][N] fp32 -> W^T hi/lo bf16 [N][K] ----
__global__ __launch_bounds__(256) void splitT_kernel(
    const float* __restrict__ W, ushortT* __restrict__ WhT, ushortT* __restrict__ WlT)
{
  __shared__ float tile[64][65];
  const int t = threadIdx.x;
  const int bk = blockIdx.y * 64, bn = blockIdx.x * 64;
  const int rr = t >> 4, c4 = (t & 15) * 4;
#pragma unroll
  for (int p = 0; p < 4; ++p) {
    int row = rr + p * 16;
    float4 v = *(const float4*)&W[(size_t)(bk + row) * DD + bn + c4];
    tile[row][c4] = v.x; tile[row][c4+1] = v.y; tile[row][c4+2] = v.z; tile[row][c4+3] = v.w;
  }
  __syncthreads();
  const int n = t & 63, ks = (t >> 6) * 16;
  union { ushortT us[16]; uint4 q[2]; } hb, lb;
#pragma unroll
  for (int j = 0; j < 16; ++j) {
    float f = tile[ks + j][n];
    ushortT h = f2bf(f);
    hb.us[j] = h;
    lb.us[j] = f2bf(f - bf2f(h));
  }
  size_t o = ((size_t)(bn + n) * DD + (size_t)(bk + ks)) >> 3;
  ((uint4*)WhT)[o] = hb.q[0]; ((uint4*)WhT)[o + 1] = hb.q[1];
  ((uint4*)WlT)[o] = lb.q[0]; ((uint4*)WlT)[o + 1] = lb.q[1];
}

// ---- projection GEMM via split-bf16 MFMA (3-combo: hh + hl + lh) ----
// 128x128 tile, BK=64, 4 waves (2x2), 16x16x32 MFMA. Optional fp32 / bf16 emits.
template<bool EMIT_B16, bool EMIT_F32>
__global__ __launch_bounds__(256, 2) void gemm_mfma(
    const ushortT* __restrict__ Axh, const ushortT* __restrict__ Axl,
    const ushortT* __restrict__ BhT, const ushortT* __restrict__ BlT,
    const float* __restrict__ bias,
    float* __restrict__ outF, ushortT* __restrict__ outH, ushortT* __restrict__ outL)
{
  __shared__ ushortT Ah[128*64], Al[128*64], Bh[128*64], Bl[128*64];
  const int t = threadIdx.x;
  const int lin = blockIdx.x;                 // 512 = 64 m-tiles x 8 n-tiles
  const int swz = (lin & 7) * 64 + (lin >> 3);
  const int m0 = (swz >> 3) * 128;
  const int n0 = (swz & 7) * 128;
  const int lane = t & 63, w = t >> 6;
  const int wr = w >> 1, wc = w & 1;
  const int fr = lane & 15, fs = lane >> 4;
  f32x4 acc[4][4];
#pragma unroll
  for (int i = 0; i < 4; ++i)
#pragma unroll
    for (int j = 0; j < 4; ++j) acc[i][j] = (f32x4){0.f, 0.f, 0.f, 0.f};

  const int srow = t >> 3, sslot = t & 7;
  for (int ks = 0; ks < DD / 64; ++ks) {
    __syncthreads();
#pragma unroll
    for (int p = 0; p < 4; ++p) {
      int row = srow + p * 32;
      size_t ga = (size_t)(m0 + row) * DD + ks * 64 + sslot * 8;
      int off = row * 64 + ((sslot ^ (row & 7)) * 8);
      *(bf16x8*)&Ah[off] = *(const bf16x8*)&Axh[ga];
      *(bf16x8*)&Al[off] = *(const bf16x8*)&Axl[ga];
    }
#pragma unroll
    for (int p = 0; p < 4; ++p) {
      int row = srow + p * 32;
      size_t go = (size_t)(n0 + row) * DD + ks * 64 + sslot * 8;
      int off = row * 64 + ((sslot ^ (row & 7)) * 8);
      *(bf16x8*)&Bh[off] = *(const bf16x8*)&BhT[go];
      *(bf16x8*)&Bl[off] = *(const bf16x8*)&BlT[go];
    }
    __syncthreads();
#pragma unroll
    for (int kk = 0; kk < 2; ++kk) {
      bf16x8 ah[4], al[4], bh[4], bl[4];
#pragma unroll
      for (int i = 0; i < 4; ++i) {
        int row = wr * 64 + i * 16 + fr;
        int off = row * 64 + (((kk * 4 + fs) ^ (row & 7)) * 8);
        ah[i] = *(const bf16x8*)&Ah[off];
        al[i] = *(const bf16x8*)&Al[off];
      }
#pragma unroll
      for (int j = 0; j < 4; ++j) {
        int row = wc * 64 + j * 16 + fr;
        int off = row * 64 + (((kk * 4 + fs) ^ (row & 7)) * 8);
        bh[j] = *(const bf16x8*)&Bh[off];
        bl[j] = *(const bf16x8*)&Bl[off];
      }
#pragma unroll
      for (int i = 0; i < 4; ++i)
#pragma unroll
        for (int j = 0; j < 4; ++j) {
          acc[i][j] = __builtin_amdgcn_mfma_f32_16x16x32_bf16(ah[i], bh[j], acc[i][j], 0, 0, 0);
          acc[i][j] = __builtin_amdgcn_mfma_f32_16x16x32_bf16(ah[i], bl[j], acc[i][j], 0, 0, 0);
          acc[i][j] = __builtin_amdgcn_mfma_f32_16x16x32_bf16(al[i], bh[j], acc[i][j], 0, 0, 0);
        }
    }
  }
  // epilogue: C/D layout col=lane&15, row=(lane>>4)*4+r
#pragma unroll
  for (int i = 0; i < 4; ++i) {
#pragma unroll
    for (int j = 0; j < 4; ++j) {
      int c = n0 + wc * 64 + j * 16 + fr;
      float bs = bias[c];
      int h = c >> 6, hd = c & 63;
#pragma unroll
      for (int r = 0; r < 4; ++r) {
        int m = m0 + wr * 64 + i * 16 + fs * 4 + r;
        int b = m >> 11, s = m & (SS - 1);
        size_t oidx = (((size_t)(b * HH + h)) * SS + s) * HD + hd;
        float val = acc[i][j][r] + bs;
        if (EMIT_F32) outF[oidx] = val;
        if (EMIT_B16) {
          ushortT hv = f2bf(val);
          outH[oidx] = hv;
          outL[oidx] = f2bf(val - bf2f(hv));
        }
      }
    }
  }
}

// ------------- per-(b,h) mean of sampled K rows and mean of V rows ----------
__global__ __launch_bounds__(256) void means_kernel(
    const float* __restrict__ K, const float* __restrict__ V,
    const int* __restrict__ sidx,
    float* __restrict__ Kmean, float* __restrict__ Vmean)
{
  __shared__ float rk[4][64], rv[4][64];
  const int bh = blockIdx.x;
  const int t = threadIdx.x;
  const int d = t & 63, p = t >> 6;
  const float* Kb = K + (size_t)bh * SS * HD;
  const float* Vb = V + (size_t)bh * SS * HD;
  float ka = 0.f, va = 0.f;
  for (int r = p * 512; r < (p + 1) * 512; ++r) {
    ka += Kb[(size_t)sidx[r] * HD + d];
    va += Vb[(size_t)r * HD + d];
  }
  rk[p][d] = ka; rv[p][d] = va;
  __syncthreads();
  if (t < 64) {
    Kmean[bh * HD + t] = (rk[0][t] + rk[1][t] + rk[2][t] + rk[3][t]) * (1.0f / SS);
    Vmean[bh * HD + t] = (rv[0][t] + rv[1][t] + rv[2][t] + rv[3][t]) * (1.0f / SS);
  }
}

// --------- M[b,h,s] = (max_u Q.K[sidx[u]] - Q.Kmean) / 8, 3-combo MFMA ------
__global__ __launch_bounds__(256, 2) void m_mfma(
    const ushortT* __restrict__ Qhg, const ushortT* __restrict__ Qlg,
    const ushortT* __restrict__ Khg, const ushortT* __restrict__ Klg,
    const int* __restrict__ sidx, const float* __restrict__ Kmean,
    float* __restrict__ M)
{
  __shared__ ushortT Qh[128*64], Ql[128*64], Kh[128*64], Kl[128*64];
  __shared__ float Mred[2][128];
  __shared__ float km[64];
  const int t = threadIdx.x;
  const int lin = blockIdx.x;                   // 1024 = 64 bh x 16 q-tiles
  const int swz = (lin & 7) * 128 + (lin >> 3);
  const int bh = swz >> 4;
  const int s0 = (swz & 15) * 128;
  const int lane = t & 63, w = t >> 6;
  const int wr = w >> 1, wc = w & 1;
  const int fr = lane & 15, fs = lane >> 4;
  if (t < 64) km[t] = Kmean[bh * HD + t];
  const int srow = t >> 3, sslot = t & 7;
#pragma unroll
  for (int p = 0; p < 4; ++p) {
    int row = srow + p * 32;
    size_t ga = ((size_t)bh * SS + s0 + row) * HD + sslot * 8;
    int off = row * 64 + ((sslot ^ (row & 7)) * 8);
    *(bf16x8*)&Qh[off] = *(const bf16x8*)&Qhg[ga];
    *(bf16x8*)&Ql[off] = *(const bf16x8*)&Qlg[ga];
  }
  float runmax[4][4];
#pragma unroll
  for (int i = 0; i < 4; ++i)
#pragma unroll
    for (int r = 0; r < 4; ++r) runmax[i][r] = -INFINITY;

  for (int u0 = 0; u0 < SS; u0 += 128) {
    __syncthreads();
#pragma unroll
    for (int p = 0; p < 4; ++p) {
      int row = srow + p * 32;
      int gr = sidx[u0 + row];
      size_t ga = ((size_t)bh * SS + gr) * HD + sslot * 8;
      int off = row * 64 + ((sslot ^ (row & 7)) * 8);
      *(bf16x8*)&Kh[off] = *(const bf16x8*)&Khg[ga];
      *(bf16x8*)&Kl[off] = *(const bf16x8*)&Klg[ga];
    }
    __syncthreads();
    f32x4 acc[4][4];
#pragma unroll
    for (int i = 0; i < 4; ++i)
#pragma unroll
      for (int j = 0; j < 4; ++j) acc[i][j] = (f32x4){0.f, 0.f, 0.f, 0.f};
#pragma unroll
    for (int kk = 0; kk < 2; ++kk) {
      bf16x8 ah[4], al[4], bh[4], bl[4];
#pragma unroll
      for (int i = 0; i < 4; ++i) {
        int row = wr * 64 + i * 16 + fr;
        int off = row * 64 + (((kk * 4 + fs) ^ (row & 7)) * 8);
        ah[i] = *(const bf16x8*)&Qh[off];
        al[i] = *(const bf16x8*)&Ql[off];
      }
#pragma unroll
      for (int j = 0; j < 4; ++j) {
        int row = wc * 64 + j * 16 + fr;
        int off = row * 64 + (((kk * 4 + fs) ^ (row & 7)) * 8);
        bh[j] = *(const bf16x8*)&Kh[off];
        bl[j] = *(const bf16x8*)&Kl[off];
      }
#pragma unroll
      for (int i = 0; i < 4; ++i)
#pragma unroll
        for (int j = 0; j < 4; ++j) {
          acc[i][j] = __builtin_amdgcn_mfma_f32_16x16x32_bf16(ah[i], bh[j], acc[i][j], 0, 0, 0);
          acc[i][j] = __builtin_amdgcn_mfma_f32_16x16x32_bf16(ah[i], bl[j], acc[i][j], 0, 0, 0);
          acc[i][j] = __builtin_amdgcn_mfma_f32_16x16x32_bf16(al[i], bh[j], acc[i][j], 0, 0, 0);
        }
    }
#pragma unroll
    for (int i = 0; i < 4; ++i)
#pragma unroll
      for (int j = 0; j < 4; ++j) {
#pragma unroll
        for (int r = 0; r < 4; ++r) runmax[i][r] = fmaxf(runmax[i][r], acc[i][j][r]);
      }
  }
#pragma unroll
  for (int i = 0; i < 4; ++i)
#pragma unroll
    for (int r = 0; r < 4; ++r) {
      float v = runmax[i][r];
      v = fmaxf(v, __shfl_xor(v, 1, 64));
      v = fmaxf(v, __shfl_xor(v, 2, 64));
      v = fmaxf(v, __shfl_xor(v, 4, 64));
      v = fmaxf(v, __shfl_xor(v, 8, 64));
      runmax[i][r] = v;
    }
  if (fr == 0) {
#pragma unroll
    for (int i = 0; i < 4; ++i)
#pragma unroll
      for (int r = 0; r < 4; ++r)
        Mred[wc][wr * 64 + i * 16 + fs * 4 + r] = runmax[i][r];
  }
  __syncthreads();
  if (t < 128) {
    float mx = fmaxf(Mred[0][t], Mred[1][t]);
    float md = 0.f;
    const ushortT* qh = &Qhg[((size_t)bh * SS + s0 + t) * HD];
    const ushortT* ql = &Qlg[((size_t)bh * SS + s0 + t) * HD];
#pragma unroll
    for (int k8 = 0; k8 < 8; ++k8) {
      bf16x8 hv = *(const bf16x8*)&qh[k8 * 8];
      bf16x8 lv = *(const bf16x8*)&ql[k8 * 8];
#pragma unroll
      for (int j = 0; j < 8; ++j)
        md += (bf2f((ushortT)hv[j]) + bf2f((ushortT)lv[j])) * km[k8 * 8 + j];
    }
    M[(size_t)bh * SS + s0 + t] = (mx - md) * 0.125f;
  }
}

// ---------------- top-38 per (b,h), ties -> lower index (lax.top_k) ---------
__global__ __launch_bounds__(256) void topk_kernel(const float* __restrict__ M,
                                                   int* __restrict__ topi)
{
  __shared__ float vals[SS];
  __shared__ float rv[256];
  __shared__ int   ri[256];
  const int t  = threadIdx.x;
  const int bh = blockIdx.x;
  for (int s = t; s < SS; s += 256) vals[s] = M[(size_t)bh * SS + s];
  __syncthreads();
  for (int it = 0; it < UU; ++it) {
    float bv = -INFINITY; int bi = 0x7fffffff;
#pragma unroll
    for (int j = 0; j < 8; ++j) {
      int s = t + j * 256;
      float v = vals[s];
      if (v > bv || (v == bv && s < bi)) { bv = v; bi = s; }
    }
    rv[t] = bv; ri[t] = bi;
    __syncthreads();
    for (int w = 128; w > 0; w >>= 1) {
      if (t < w) {
        float ov = rv[t + w]; int oi = ri[t + w];
        if (ov > rv[t] || (ov == rv[t] && oi < ri[t])) { rv[t] = ov; ri[t] = oi; }
      }
      __syncthreads();
    }
    if (t == 0) { topi[bh * UU + it] = ri[0]; vals[ri[0]] = -INFINITY; }
    __syncthreads();
  }
}

// ---------- flash attention over selected queries, split over S -------------
__global__ __launch_bounds__(256) void attn_flash(
    const ushortT* __restrict__ Qhg, const ushortT* __restrict__ Qlg,
    const float* __restrict__ K, const float* __restrict__ V,
    const int* __restrict__ topi,
    float* __restrict__ pacc, float* __restrict__ pm, float* __restrict__ pl)
{
  __shared__ float Qt[64][68];
  __shared__ float KV[64][68];
  __shared__ float Ps[64][68];
  __shared__ float redA[16][64];
  __shared__ float redB[16][64];
  __shared__ float mrow[64], lrow[64], scl[64];
  const int t  = threadIdx.x;
  const int bh = blockIdx.x;
  const int sp = blockIdx.y;
  const float* Kb = K + (size_t)bh * SS * HD;
  const float* Vb = V + (size_t)bh * SS * HD;
  if (t < 64) { mrow[t] = -INFINITY; lrow[t] = 0.f; }
  {
    int q = t >> 2, k4 = (t & 3) * 16;
    float fv[16];
#pragma unroll
    for (int e = 0; e < 16; ++e) fv[e] = 0.f;
    if (q < UU) {
      int qidx = topi[bh * UU + q];
      size_t ga = ((size_t)bh * SS + qidx) * HD + k4;
      bf16x8 h0 = *(const bf16x8*)&Qhg[ga];
      bf16x8 h1 = *(const bf16x8*)&Qhg[ga + 8];
      bf16x8 l0 = *(const bf16x8*)&Qlg[ga];
      bf16x8 l1 = *(const bf16x8*)&Qlg[ga + 8];
#pragma unroll
      for (int j = 0; j < 8; ++j) {
        fv[j]     = bf2f((ushortT)h0[j]) + bf2f((ushortT)l0[j]);
        fv[8 + j] = bf2f((ushortT)h1[j]) + bf2f((ushortT)l1[j]);
      }
    }
#pragma unroll
    for (int e = 0; e < 16; ++e) Qt[k4 + e][q] = fv[e];
  }
  const int q4 = (t & 15) * 4, j4g = (t >> 4) * 4, d4 = (t >> 4) * 4;
  const int lj = t >> 2, lk4 = (t & 3) * 16;
  float acc[4][4] = {};
  for (int s0 = sp * SPLEN; s0 < (sp + 1) * SPLEN; s0 += 64) {
    __syncthreads();
#pragma unroll
    for (int i = 0; i < 4; ++i) {
      float4 v = *(const float4*)&Kb[(size_t)(s0 + lj) * HD + lk4 + 4 * i];
      KV[lk4 + 4*i + 0][lj] = v.x; KV[lk4 + 4*i + 1][lj] = v.y;
      KV[lk4 + 4*i + 2][lj] = v.z; KV[lk4 + 4*i + 3][lj] = v.w;
    }
    __syncthreads();
    float sacc[4][4] = {};
#pragma unroll 16
    for (int k = 0; k < 64; ++k) {
      float4 a = *(const float4*)&Qt[k][q4];
      float4 b = *(const float4*)&KV[k][j4g];
      sacc[0][0] += a.x*b.x; sacc[0][1] += a.x*b.y; sacc[0][2] += a.x*b.z; sacc[0][3] += a.x*b.w;
      sacc[1][0] += a.y*b.x; sacc[1][1] += a.y*b.y; sacc[1][2] += a.y*b.z; sacc[1][3] += a.y*b.w;
      sacc[2][0] += a.z*b.x; sacc[2][1] += a.z*b.y; sacc[2][2] += a.z*b.z; sacc[2][3] += a.z*b.w;
      sacc[3][0] += a.w*b.x; sacc[3][1] += a.w*b.y; sacc[3][2] += a.w*b.z; sacc[3][3] += a.w*b.w;
    }
#pragma unroll
    for (int i = 0; i < 4; ++i) {
      float mx = fmaxf(fmaxf(sacc[i][0], sacc[i][1]), fmaxf(sacc[i][2], sacc[i][3]));
      redA[t >> 4][q4 + i] = mx;
    }
    __syncthreads();
    if (t < 64) {
      float mx = redA[0][t];
#pragma unroll
      for (int g = 1; g < 16; ++g) mx = fmaxf(mx, redA[g][t]);
      float mn = fmaxf(mrow[t], mx * 0.125f);
      scl[t] = __expf(mrow[t] - mn);
      mrow[t] = mn;
    }
    __syncthreads();
    float4 vld[4];
#pragma unroll
    for (int i = 0; i < 4; ++i)
      vld[i] = *(const float4*)&Vb[(size_t)(s0 + lj) * HD + lk4 + 4 * i];
    float psum[4] = {};
#pragma unroll
    for (int i = 0; i < 4; ++i) {
#pragma unroll
      for (int j = 0; j < 4; ++j) {
        float e = __expf(sacc[i][j] * 0.125f - mrow[q4 + i]);
        Ps[j4g + j][q4 + i] = e;
        psum[i] += e;
      }
      redB[t >> 4][q4 + i] = psum[i];
    }
#pragma unroll
    for (int i = 0; i < 4; ++i)
      *(float4*)&KV[lj][lk4 + 4 * i] = vld[i];
    __syncthreads();
    if (t < 64) {
      float ts = redB[0][t];
#pragma unroll
      for (int g = 1; g < 16; ++g) ts += redB[g][t];
      lrow[t] = lrow[t] * scl[t] + ts;
    }
#pragma unroll
    for (int i = 0; i < 4; ++i) {
      float fsc = scl[q4 + i];
      acc[i][0] *= fsc; acc[i][1] *= fsc; acc[i][2] *= fsc; acc[i][3] *= fsc;
    }
#pragma unroll 16
    for (int j = 0; j < 64; ++j) {
      float4 a = *(const float4*)&Ps[j][q4];
      float4 b = *(const float4*)&KV[j][d4];
      acc[0][0] += a.x*b.x; acc[0][1] += a.x*b.y; acc[0][2] += a.x*b.z; acc[0][3] += a.x*b.w;
      acc[1][0] += a.y*b.x; acc[1][1] += a.y*b.y; acc[1][2] += a.y*b.z; acc[1][3] += a.y*b.w;
      acc[2][0] += a.z*b.x; acc[2][1] += a.z*b.y; acc[2][2] += a.z*b.z; acc[2][3] += a.z*b.w;
      acc[3][0] += a.w*b.x; acc[3][1] += a.w*b.y; acc[3][2] += a.w*b.z; acc[3][3] += a.w*b.w;
    }
  }
  const size_t pb = ((size_t)bh * NSPLIT + sp) * QPAD;
#pragma unroll
  for (int i = 0; i < 4; ++i) {
    int q = q4 + i;
    if (q < UU) {
#pragma unroll
      for (int j = 0; j < 4; ++j)
        pacc[(pb + q) * HD + d4 + j] = acc[i][j];
    }
  }
  if (t < UU) { pm[pb + t] = mrow[t]; pl[pb + t] = lrow[t]; }
}

__global__ __launch_bounds__(256) void attn_combine(
    const float* __restrict__ pacc, const float* __restrict__ pm,
    const float* __restrict__ pl, float* __restrict__ ctx)
{
  const int t  = threadIdx.x;
  const int bh = blockIdx.x;
  const int d = t & 63, qg = t >> 6;
  for (int q = qg; q < UU; q += 4) {
    float m0 = pm[((size_t)bh * NSPLIT + 0) * QPAD + q];
    float m1 = pm[((size_t)bh * NSPLIT + 1) * QPAD + q];
    float m2 = pm[((size_t)bh * NSPLIT + 2) * QPAD + q];
    float m3 = pm[((size_t)bh * NSPLIT + 3) * QPAD + q];
    float ms = fmaxf(fmaxf(m0, m1), fmaxf(m2, m3));
    float w0 = __expf(m0 - ms), w1 = __expf(m1 - ms), w2 = __expf(m2 - ms), w3 = __expf(m3 - ms);
    float l = w0 * pl[((size_t)bh * NSPLIT + 0) * QPAD + q]
            + w1 * pl[((size_t)bh * NSPLIT + 1) * QPAD + q]
            + w2 * pl[((size_t)bh * NSPLIT + 2) * QPAD + q]
            + w3 * pl[((size_t)bh * NSPLIT + 3) * QPAD + q];
    float c = w0 * pacc[(((size_t)bh * NSPLIT + 0) * QPAD + q) * HD + d]
            + w1 * pacc[(((size_t)bh * NSPLIT + 1) * QPAD + q) * HD + d]
            + w2 * pacc[(((size_t)bh * NSPLIT + 2) * QPAD + q) * HD + d]
            + w3 * pacc[(((size_t)bh * NSPLIT + 3) * QPAD + q) * HD + d];
    ctx[((size_t)bh * UU + q) * HD + d] = c / l;
  }
}

__global__ void base_kernel(const float* __restrict__ Vmean, const float* __restrict__ Wo,
                            const float* __restrict__ bo, float* __restrict__ base)
{
  const int c = blockIdx.x * 256 + threadIdx.x;
  float acc[BB] = {};
  for (int k = 0; k < DD; ++k) {
    float w = Wo[(size_t)k * DD + c];
#pragma unroll
    for (int b = 0; b < BB; ++b) acc[b] += Vmean[b * DD + k] * w;
  }
#pragma unroll
  for (int b = 0; b < BB; ++b) base[b * DD + c] = acc[b] + bo[c];
}

__global__ void fill_kernel(const float* __restrict__ base, float* __restrict__ out)
{
  size_t i = (size_t)blockIdx.x * 256 + threadIdx.x;
  float4 bv = ((const float4*)base)[(i >> 19) * 256 + (i & 255)];
  ((float4*)out)[i] = bv;
}

__global__ __launch_bounds__(256) void scatter_kernel(
    const float* __restrict__ ctx, const float* __restrict__ Vmean,
    const int* __restrict__ topi, const float* __restrict__ Wo,
    float* __restrict__ out)
{
  __shared__ float delta[64];
  const int t  = threadIdx.x;
  const int bh = blockIdx.x;
  const int u  = blockIdx.y;
  const int b = bh >> 4, h = bh & 15;
  const int s = topi[bh * UU + u];
  if (t < 64) delta[t] = ctx[((size_t)bh * UU + u) * HD + t] - Vmean[bh * HD + t];
  __syncthreads();
  float* orow = out + ((size_t)b * SS + s) * DD;
#pragma unroll
  for (int j = 0; j < 4; ++j) {
    int c = t + j * 256;
    float acc = 0.f;
#pragma unroll 8
    for (int d = 0; d < 64; ++d) acc += delta[d] * Wo[(size_t)(h * HD + d) * DD + c];
    atomicAdd(&orow[c], acc);
  }
}

extern "C" void kernel_launch(void* const* d_in, const int* in_sizes, int n_in,
                              void* d_out, int out_size, void* d_ws, size_t ws_size,
                              hipStream_t stream) {
  const float* x  = (const float*)d_in[0];
  const float* Wq = (const float*)d_in[1];
  const float* bq = (const float*)d_in[2];
  const float* Wk = (const float*)d_in[3];
  const float* bk = (const float*)d_in[4];
  const float* Wv = (const float*)d_in[5];
  const float* bv = (const float*)d_in[6];
  const float* Wo = (const float*)d_in[7];
  const float* bo = (const float*)d_in[8];
  const int* sidx = (const int*)d_in[9];
  float* out = (float*)d_out;

  float* f     = (float*)d_ws;
  float* K     = f;                          // QSZ
  float* V     = f + (size_t)QSZ;            // QSZ
  float* Kmean = f + (size_t)2 * QSZ;
  float* Vmean = Kmean + BH * HD;
  float* Mbuf  = Vmean + BH * HD;
  float* base  = Mbuf + (size_t)BH * SS;
  float* ctx   = base + BB * DD;
  float* pacc  = ctx + (size_t)BH * UU * HD;
  float* pm    = pacc + (size_t)BH * NSPLIT * QPAD * HD;
  float* pl    = pm + (size_t)BH * NSPLIT * QPAD;
  int*   topi  = (int*)(pl + (size_t)BH * NSPLIT * QPAD);
  ushortT* usp = (ushortT*)(topi + 1024);
  ushortT* WqhT = usp;                          // DD*DD each
  ushortT* WqlT = WqhT + (size_t)DD * DD;
  ushortT* WkhT = WqlT + (size_t)DD * DD;
  ushortT* WklT = WkhT + (size_t)DD * DD;
  ushortT* WvhT = WklT + (size_t)DD * DD;
  ushortT* WvlT = WvhT + (size_t)DD * DD;
  ushortT* xh   = WvlT + (size_t)DD * DD;       // NROWS*DD
  ushortT* xl   = xh + (size_t)NROWS * DD;
  ushortT* Qhg  = xl + (size_t)NROWS * DD;      // QSZ
  ushortT* Qlg  = Qhg + (size_t)QSZ;
  ushortT* Khg  = Qlg + (size_t)QSZ;
  ushortT* Klg  = Khg + (size_t)QSZ;

  split_x<<<NROWS * DD / (256 * 8), 256, 0, stream>>>(x, xh, xl);
  dim3 gs(16, 16);
  splitT_kernel<<<gs, 256, 0, stream>>>(Wq, WqhT, WqlT);
  splitT_kernel<<<gs, 256, 0, stream>>>(Wk, WkhT, WklT);
  splitT_kernel<<<gs, 256, 0, stream>>>(Wv, WvhT, WvlT);
  gemm_mfma<true, false><<<512, 256, 0, stream>>>(xh, xl, WqhT, WqlT, bq, nullptr, Qhg, Qlg);
  gemm_mfma<true, true ><<<512, 256, 0, stream>>>(xh, xl, WkhT, WklT, bk, K, Khg, Klg);
  gemm_mfma<false, true><<<512, 256, 0, stream>>>(xh, xl, WvhT, WvlT, bv, V, nullptr, nullptr);
  means_kernel<<<BH, 256, 0, stream>>>(K, V, sidx, Kmean, Vmean);
  m_mfma<<<1024, 256, 0, stream>>>(Qhg, Qlg, Khg, Klg, sidx, Kmean, Mbuf);
  topk_kernel<<<BH, 256, 0, stream>>>(Mbuf, topi);
  attn_flash<<<dim3(BH, NSPLIT), 256, 0, stream>>>(Qhg, Qlg, K, V, topi, pacc, pm, pl);
  attn_combine<<<BH, 256, 0, stream>>>(pacc, pm, pl, ctx);
  base_kernel<<<DD / 256, 256, 0, stream>>>(Vmean, Wo, bo, base);
  fill_kernel<<<(NROWS * DD / 4) / 256, 256, 0, stream>>>(base, out);
  scatter_kernel<<<dim3(BH, UU), 256, 0, stream>>>(ctx, Vmean, topi, Wo, out);
}

// Round 6
// 473.318 us; speedup vs baseline: 3.9920x; 1.0434x over previous
//
#include <hip/hip_runtime.h>
#include <math.h>
#include <stdint.h>
#include <stddef.h>

#define BB 4
#define SS 2048
#define DD 1024
#define HH 16
#define HD 64
#define UU 38
#define BH (BB*HH)        // 64
#define NROWS (BB*SS)     // 8192
#define QSZ (BB*HH*SS*HD) // 8388608 floats per Q/K/V
#define NSPLIT 4
#define SPLEN (SS/NSPLIT) // 512
#define QPAD 40

typedef unsigned short ushortT;
typedef unsigned int u32;
typedef __attribute__((ext_vector_type(8))) short bf16x8;
typedef __attribute__((ext_vector_type(4))) float f32x4;

static __device__ __forceinline__ ushortT f2bf(float f) {
  union { float f; unsigned int u; } v; v.f = f;
  unsigned int r = v.u + 0x7fffu + ((v.u >> 16) & 1u);  // round-to-nearest-even
  return (ushortT)(r >> 16);
}
static __device__ __forceinline__ float bf2f(ushortT h) {
  union { unsigned int u; float f; } v; v.u = ((unsigned int)h) << 16; return v.f;
}
// async global->LDS, 16B per lane; lds dest must be wave-uniform base (HW adds lane*16)
static __device__ __forceinline__ void gld16(const void* g, void* l) {
  __builtin_amdgcn_global_load_lds((const __attribute__((address_space(1))) u32*)g,
                                   (__attribute__((address_space(3))) u32*)l, 16, 0, 0);
}

// ---- x fp32 -> xh/xl bf16 (row-major, same layout) ----
__global__ __launch_bounds__(256) void split_x(
    const float* __restrict__ x, ushortT* __restrict__ xh, ushortT* __restrict__ xl)
{
  size_t i = ((size_t)blockIdx.x * 256 + threadIdx.x) * 8;
  float4 v0 = *(const float4*)&x[i];
  float4 v1 = *(const float4*)&x[i + 4];
  float fv[8] = {v0.x, v0.y, v0.z, v0.w, v1.x, v1.y, v1.z, v1.w};
  bf16x8 hv, lv;
#pragma unroll
  for (int j = 0; j < 8; ++j) {
    ushortT h = f2bf(fv[j]);
    hv[j] = (short)h;
    lv[j] = (short)f2bf(fv[j] - bf2f(h));
  }
  *(bf16x8*)&xh[i] = hv;
  *(bf16x8*)&xl[i] = lv;
}

// ---- W [K][N] fp32 -> W^T hi/lo bf16 [N][K] ----
__global__ __launch_bounds__(256) void splitT_kernel(
    const float* __restrict__ W, ushortT* __restrict__ WhT, ushortT* __restrict__ WlT)
{
  __shared__ float tile[64][65];
  const int t = threadIdx.x;
  const int bk = blockIdx.y * 64, bn = blockIdx.x * 64;
  const int rr = t >> 4, c4 = (t & 15) * 4;
#pragma unroll
  for (int p = 0; p < 4; ++p) {
    int row = rr + p * 16;
    float4 v = *(const float4*)&W[(size_t)(bk + row) * DD + bn + c4];
    tile[row][c4] = v.x; tile[row][c4+1] = v.y; tile[row][c4+2] = v.z; tile[row][c4+3] = v.w;
  }
  __syncthreads();
  const int n = t & 63, ks = (t >> 6) * 16;
  union { ushortT us[16]; uint4 q[2]; } hb, lb;
#pragma unroll
  for (int j = 0; j < 16; ++j) {
    float f = tile[ks + j][n];
    ushortT h = f2bf(f);
    hb.us[j] = h;
    lb.us[j] = f2bf(f - bf2f(h));
  }
  size_t o = ((size_t)(bn + n) * DD + (size_t)(bk + ks)) >> 3;
  ((uint4*)WhT)[o] = hb.q[0]; ((uint4*)WhT)[o + 1] = hb.q[1];
  ((uint4*)WlT)[o] = lb.q[0]; ((uint4*)WlT)[o + 1] = lb.q[1];
}

// ---- dedupe sample_idx -> unique list padded to x128 with uidx[0] ----
__global__ __launch_bounds__(256) void dedupe_kernel(
    const int* __restrict__ sidx, int* __restrict__ uidx, int* __restrict__ ucount)
{
  __shared__ unsigned bm[64];
  __shared__ int base[64];
  const int t = threadIdx.x;
  if (t < 64) bm[t] = 0;
  __syncthreads();
  for (int s = t; s < SS; s += 256) {
    int v = sidx[s];                       // FIX: mark the sampled VALUE, not the position
    atomicOr(&bm[v >> 5], 1u << (v & 31));
  }
  __syncthreads();
  if (t < 64) {  // one full wave
    int c = __popc(bm[t]);
    int pre = c;
#pragma unroll
    for (int off = 1; off < 64; off <<= 1) {
      int o = __shfl_up(pre, off, 64);
      if (t >= off) pre += o;
    }
    base[t] = pre - c;
    if (t == 63) ucount[0] = pre;
  }
  __syncthreads();
  if (t < 64) {
    unsigned m = bm[t];
    int o = base[t];
    while (m) {
      int b = __ffs(m) - 1;
      uidx[o++] = t * 32 + b;
      m &= m - 1;
    }
  }
  __syncthreads();
  int total = ucount[0];
  int padded = (total + 127) & ~127;
  int first = uidx[0];
  for (int i = total + t; i < padded; i += 256) uidx[i] = first;
}

// ---- projection GEMM, virtual-K=3072 standard bf16 MFMA (hh + lh + hl) ----
// 128x128 tile, BK=64, 4 waves (2x2), global_load_lds staging, swizzled src+read.
template<bool EMIT_B16, bool EMIT_F32>
__global__ __launch_bounds__(256, 3) void gemm_mfma(
    const ushortT* __restrict__ Axh, const ushortT* __restrict__ Axl,
    const ushortT* __restrict__ BhT, const ushortT* __restrict__ BlT,
    const float* __restrict__ bias,
    float* __restrict__ outF, ushortT* __restrict__ outH, ushortT* __restrict__ outL)
{
  __shared__ ushortT As[128 * 64];
  __shared__ ushortT Bs[128 * 64];
  const int t = threadIdx.x;
  const int lin = blockIdx.x;                  // 512 = 64 m-tiles x 8 n-tiles
  const int swz = (lin & 7) * 64 + (lin >> 3); // XCD-contiguous chunks
  const int m0 = (swz >> 3) * 128;
  const int n0 = (swz & 7) * 128;
  const int lane = t & 63, w = t >> 6;
  const int wr = w >> 1, wc = w & 1;
  const int fr = lane & 15, fs = lane >> 4;
  const int srow = t >> 3, sslot = t & 7;      // staging: row, slot per thread
  f32x4 acc[4][4];
#pragma unroll
  for (int i = 0; i < 4; ++i)
#pragma unroll
    for (int j = 0; j < 4; ++j) acc[i][j] = (f32x4){0.f, 0.f, 0.f, 0.f};

  for (int kt = 0; kt < 48; ++kt) {
    const int seg = kt >> 4;
    const int rk0 = (kt & 15) * 64;
    const ushortT* a_src = (seg == 1) ? Axl : Axh;
    const ushortT* b_src = (seg == 2) ? BlT : BhT;
    __syncthreads();  // previous tile fully consumed
#pragma unroll
    for (int is = 0; is < 4; ++is) {
      int row = is * 32 + srow;
      int soff = ((sslot ^ (row & 7)) * 8);    // inverse-swizzled global source
      int cb = (is * 256 + (t & 192)) * 8;     // wave-uniform LDS chunk base (ushort units)
      gld16(&a_src[(size_t)(m0 + row) * DD + rk0 + soff], &As[cb]);
      gld16(&b_src[(size_t)(n0 + row) * DD + rk0 + soff], &Bs[cb]);
    }
    __syncthreads();  // drains vmcnt(0)
#pragma unroll
    for (int kk = 0; kk < 2; ++kk) {
      bf16x8 af[4], bf[4];
#pragma unroll
      for (int i = 0; i < 4; ++i) {
        int row = wr * 64 + i * 16 + fr;
        af[i] = *(const bf16x8*)&As[row * 64 + (((kk * 4 + fs) ^ (row & 7)) * 8)];
      }
#pragma unroll
      for (int j = 0; j < 4; ++j) {
        int row = wc * 64 + j * 16 + fr;
        bf[j] = *(const bf16x8*)&Bs[row * 64 + (((kk * 4 + fs) ^ (row & 7)) * 8)];
      }
#pragma unroll
      for (int i = 0; i < 4; ++i)
#pragma unroll
        for (int j = 0; j < 4; ++j)
          acc[i][j] = __builtin_amdgcn_mfma_f32_16x16x32_bf16(af[i], bf[j], acc[i][j], 0, 0, 0);
    }
  }
  // epilogue: C/D layout col=lane&15, row=(lane>>4)*4+r
#pragma unroll
  for (int i = 0; i < 4; ++i) {
#pragma unroll
    for (int j = 0; j < 4; ++j) {
      int c = n0 + wc * 64 + j * 16 + fr;
      float bs = bias[c];
      int h = c >> 6, hd = c & 63;
#pragma unroll
      for (int r = 0; r < 4; ++r) {
        int m = m0 + wr * 64 + i * 16 + fs * 4 + r;
        int b = m >> 11, s = m & (SS - 1);
        size_t oidx = (((size_t)(b * HH + h)) * SS + s) * HD + hd;
        float val = acc[i][j][r] + bs;
        if (EMIT_F32) outF[oidx] = val;
        if (EMIT_B16) {
          ushortT hv = f2bf(val);
          outH[oidx] = hv;
          outL[oidx] = f2bf(val - bf2f(hv));
        }
      }
    }
  }
}

// ------------- per-(b,h) mean of sampled K rows and mean of V rows ----------
__global__ __launch_bounds__(256) void means_kernel(
    const float* __restrict__ K, const float* __restrict__ V,
    const int* __restrict__ sidx,
    float* __restrict__ Kmean, float* __restrict__ Vmean)
{
  __shared__ float rk[4][64], rv[4][64];
  const int bh = blockIdx.x;
  const int t = threadIdx.x;
  const int d = t & 63, p = t >> 6;
  const float* Kb = K + (size_t)bh * SS * HD;
  const float* Vb = V + (size_t)bh * SS * HD;
  float ka = 0.f, va = 0.f;
  for (int r = p * 512; r < (p + 1) * 512; ++r) {
    ka += Kb[(size_t)sidx[r] * HD + d];
    va += Vb[(size_t)r * HD + d];
  }
  rk[p][d] = ka; rv[p][d] = va;
  __syncthreads();
  if (t < 64) {
    Kmean[bh * HD + t] = (rk[0][t] + rk[1][t] + rk[2][t] + rk[3][t]) * (1.0f / SS);
    Vmean[bh * HD + t] = (rv[0][t] + rv[1][t] + rv[2][t] + rv[3][t]) * (1.0f / SS);
  }
}

// --------- M[b,h,s] = (max_u Q.K[uidx[u]] - Q.Kmean) / 8, 3-combo MFMA ------
__global__ __launch_bounds__(256, 2) void m_mfma(
    const ushortT* __restrict__ Qhg, const ushortT* __restrict__ Qlg,
    const ushortT* __restrict__ Khg, const ushortT* __restrict__ Klg,
    const int* __restrict__ uidx, const int* __restrict__ ucount,
    const float* __restrict__ Kmean, float* __restrict__ M)
{
  __shared__ ushortT QhL[128 * 64], QlL[128 * 64], KhL[128 * 64], KlL[128 * 64];
  __shared__ float Mred[2][128];
  __shared__ float km[64];
  const int t = threadIdx.x;
  const int lin = blockIdx.x;                   // 1024 = 64 bh x 16 q-tiles
  const int swz = (lin & 7) * 128 + (lin >> 3);
  const int bh = swz >> 4;
  const int s0 = (swz & 15) * 128;
  const int lane = t & 63, w = t >> 6;
  const int wr = w >> 1, wc = w & 1;
  const int fr = lane & 15, fs = lane >> 4;
  if (t < 64) km[t] = Kmean[bh * HD + t];
  const int srow = t >> 3, sslot = t & 7;
  const int ntiles = (ucount[0] + 127) >> 7;
  // stage Q tiles once (async; first loop barrier pair drains)
#pragma unroll
  for (int is = 0; is < 4; ++is) {
    int row = is * 32 + srow;
    int soff = ((sslot ^ (row & 7)) * 8);
    int cb = (is * 256 + (t & 192)) * 8;
    size_t ga = ((size_t)bh * SS + s0 + row) * HD + soff;
    gld16(&Qhg[ga], &QhL[cb]);
    gld16(&Qlg[ga], &QlL[cb]);
  }
  float runmax[4][4];
#pragma unroll
  for (int i = 0; i < 4; ++i)
#pragma unroll
    for (int r = 0; r < 4; ++r) runmax[i][r] = -INFINITY;

  for (int ui = 0; ui < ntiles; ++ui) {
    __syncthreads();  // prev K tile consumed (also drains Q staging on ui=0)
#pragma unroll
    for (int is = 0; is < 4; ++is) {
      int row = is * 32 + srow;
      int gr = uidx[ui * 128 + row];
      int soff = ((sslot ^ (row & 7)) * 8);
      int cb = (is * 256 + (t & 192)) * 8;
      size_t ga = ((size_t)bh * SS + gr) * HD + soff;
      gld16(&Khg[ga], &KhL[cb]);
      gld16(&Klg[ga], &KlL[cb]);
    }
    __syncthreads();  // vmcnt(0) drained
    f32x4 acc[4][4];
#pragma unroll
    for (int i = 0; i < 4; ++i)
#pragma unroll
      for (int j = 0; j < 4; ++j) acc[i][j] = (f32x4){0.f, 0.f, 0.f, 0.f};
#pragma unroll
    for (int kk = 0; kk < 2; ++kk) {
      bf16x8 ah[4], al[4], bh[4], bl[4];
#pragma unroll
      for (int i = 0; i < 4; ++i) {
        int row = wr * 64 + i * 16 + fr;
        int off = row * 64 + (((kk * 4 + fs) ^ (row & 7)) * 8);
        ah[i] = *(const bf16x8*)&QhL[off];
        al[i] = *(const bf16x8*)&QlL[off];
      }
#pragma unroll
      for (int j = 0; j < 4; ++j) {
        int row = wc * 64 + j * 16 + fr;
        int off = row * 64 + (((kk * 4 + fs) ^ (row & 7)) * 8);
        bh[j] = *(const bf16x8*)&KhL[off];
        bl[j] = *(const bf16x8*)&KlL[off];
      }
#pragma unroll
      for (int i = 0; i < 4; ++i)
#pragma unroll
        for (int j = 0; j < 4; ++j) {
          acc[i][j] = __builtin_amdgcn_mfma_f32_16x16x32_bf16(ah[i], bh[j], acc[i][j], 0, 0, 0);
          acc[i][j] = __builtin_amdgcn_mfma_f32_16x16x32_bf16(ah[i], bl[j], acc[i][j], 0, 0, 0);
          acc[i][j] = __builtin_amdgcn_mfma_f32_16x16x32_bf16(al[i], bh[j], acc[i][j], 0, 0, 0);
        }
    }
#pragma unroll
    for (int i = 0; i < 4; ++i)
#pragma unroll
      for (int j = 0; j < 4; ++j)
#pragma unroll
        for (int r = 0; r < 4; ++r) runmax[i][r] = fmaxf(runmax[i][r], acc[i][j][r]);
  }
#pragma unroll
  for (int i = 0; i < 4; ++i)
#pragma unroll
    for (int r = 0; r < 4; ++r) {
      float v = runmax[i][r];
      v = fmaxf(v, __shfl_xor(v, 1, 64));
      v = fmaxf(v, __shfl_xor(v, 2, 64));
      v = fmaxf(v, __shfl_xor(v, 4, 64));
      v = fmaxf(v, __shfl_xor(v, 8, 64));
      runmax[i][r] = v;
    }
  if (fr == 0) {
#pragma unroll
    for (int i = 0; i < 4; ++i)
#pragma unroll
      for (int r = 0; r < 4; ++r)
        Mred[wc][wr * 64 + i * 16 + fs * 4 + r] = runmax[i][r];
  }
  __syncthreads();
  if (t < 128) {
    float mx = fmaxf(Mred[0][t], Mred[1][t]);
    float md = 0.f;
    const ushortT* qh = &Qhg[((size_t)bh * SS + s0 + t) * HD];
    const ushortT* ql = &Qlg[((size_t)bh * SS + s0 + t) * HD];
#pragma unroll
    for (int k8 = 0; k8 < 8; ++k8) {
      bf16x8 hv = *(const bf16x8*)&qh[k8 * 8];
      bf16x8 lv = *(const bf16x8*)&ql[k8 * 8];
#pragma unroll
      for (int j = 0; j < 8; ++j)
        md += (bf2f((ushortT)hv[j]) + bf2f((ushortT)lv[j])) * km[k8 * 8 + j];
    }
    M[(size_t)bh * SS + s0 + t] = (mx - md) * 0.125f;
  }
}

// ------- top-38 per (b,h): register-resident + wave shfl reduce -------------
__global__ __launch_bounds__(256) void topk_kernel(const float* __restrict__ M,
                                                   int* __restrict__ topi)
{
  __shared__ float rw[4];
  __shared__ int   ri4[4];
  __shared__ int   winner;
  const int t = threadIdx.x, bh = blockIdx.x;
  const int lane = t & 63, w = t >> 6;
  float v[8];
#pragma unroll
  for (int j = 0; j < 8; ++j) v[j] = M[(size_t)bh * SS + t + j * 256];
  for (int it = 0; it < UU; ++it) {
    float bv = v[0]; int bj = 0;
#pragma unroll
    for (int j = 1; j < 8; ++j) if (v[j] > bv) { bv = v[j]; bj = j; }
    int bs = t + bj * 256;
#pragma unroll
    for (int off = 32; off > 0; off >>= 1) {
      float ov = __shfl_xor(bv, off, 64);
      int os = __shfl_xor(bs, off, 64);
      if (ov > bv || (ov == bv && os < bs)) { bv = ov; bs = os; }
    }
    if (lane == 0) { rw[w] = bv; ri4[w] = bs; }
    __syncthreads();
    if (t == 0) {
      float fv = rw[0]; int fsx = ri4[0];
#pragma unroll
      for (int g = 1; g < 4; ++g)
        if (rw[g] > fv || (rw[g] == fv && ri4[g] < fsx)) { fv = rw[g]; fsx = ri4[g]; }
      topi[bh * UU + it] = fsx;
      winner = fsx;
    }
    __syncthreads();
    int wi = winner;
    if ((wi & 255) == t) {
      int jj = wi >> 8;
#pragma unroll
      for (int j = 0; j < 8; ++j) if (j == jj) v[j] = -INFINITY;  // static index
    }
  }
}

// ---------- flash attention over selected queries, split over S -------------
__global__ __launch_bounds__(256) void attn_flash(
    const ushortT* __restrict__ Qhg, const ushortT* __restrict__ Qlg,
    const float* __restrict__ K, const float* __restrict__ V,
    const int* __restrict__ topi,
    float* __restrict__ pacc, float* __restrict__ pm, float* __restrict__ pl)
{
  __shared__ float Qt[64][68];
  __shared__ float KV[64][68];
  __shared__ float Ps[64][68];
  __shared__ float redA[16][64];
  __shared__ float redB[16][64];
  __shared__ float mrow[64], lrow[64], scl[64];
  const int t  = threadIdx.x;
  const int bh = blockIdx.x;
  const int sp = blockIdx.y;
  const float* Kb = K + (size_t)bh * SS * HD;
  const float* Vb = V + (size_t)bh * SS * HD;
  if (t < 64) { mrow[t] = -INFINITY; lrow[t] = 0.f; }
  {
    int q = t >> 2, k4 = (t & 3) * 16;
    float fv[16];
#pragma unroll
    for (int e = 0; e < 16; ++e) fv[e] = 0.f;
    if (q < UU) {
      int qidx = topi[bh * UU + q];
      size_t ga = ((size_t)bh * SS + qidx) * HD + k4;
      bf16x8 h0 = *(const bf16x8*)&Qhg[ga];
      bf16x8 h1 = *(const bf16x8*)&Qhg[ga + 8];
      bf16x8 l0 = *(const bf16x8*)&Qlg[ga];
      bf16x8 l1 = *(const bf16x8*)&Qlg[ga + 8];
#pragma unroll
      for (int j = 0; j < 8; ++j) {
        fv[j]     = bf2f((ushortT)h0[j]) + bf2f((ushortT)l0[j]);
        fv[8 + j] = bf2f((ushortT)h1[j]) + bf2f((ushortT)l1[j]);
      }
    }
#pragma unroll
    for (int e = 0; e < 16; ++e) Qt[k4 + e][q] = fv[e];
  }
  const int q4 = (t & 15) * 4, j4g = (t >> 4) * 4, d4 = (t >> 4) * 4;
  const int lj = t >> 2, lk4 = (t & 3) * 16;
  float acc[4][4] = {};
  for (int s0 = sp * SPLEN; s0 < (sp + 1) * SPLEN; s0 += 64) {
    __syncthreads();
#pragma unroll
    for (int i = 0; i < 4; ++i) {
      float4 v = *(const float4*)&Kb[(size_t)(s0 + lj) * HD + lk4 + 4 * i];
      KV[lk4 + 4*i + 0][lj] = v.x; KV[lk4 + 4*i + 1][lj] = v.y;
      KV[lk4 + 4*i + 2][lj] = v.z; KV[lk4 + 4*i + 3][lj] = v.w;
    }
    __syncthreads();
    float sacc[4][4] = {};
#pragma unroll 16
    for (int k = 0; k < 64; ++k) {
      float4 a = *(const float4*)&Qt[k][q4];
      float4 b = *(const float4*)&KV[k][j4g];
      sacc[0][0] += a.x*b.x; sacc[0][1] += a.x*b.y; sacc[0][2] += a.x*b.z; sacc[0][3] += a.x*b.w;
      sacc[1][0] += a.y*b.x; sacc[1][1] += a.y*b.y; sacc[1][2] += a.y*b.z; sacc[1][3] += a.y*b.w;
      sacc[2][0] += a.z*b.x; sacc[2][1] += a.z*b.y; sacc[2][2] += a.z*b.z; sacc[2][3] += a.z*b.w;
      sacc[3][0] += a.w*b.x; sacc[3][1] += a.w*b.y; sacc[3][2] += a.w*b.z; sacc[3][3] += a.w*b.w;
    }
#pragma unroll
    for (int i = 0; i < 4; ++i) {
      float mx = fmaxf(fmaxf(sacc[i][0], sacc[i][1]), fmaxf(sacc[i][2], sacc[i][3]));
      redA[t >> 4][q4 + i] = mx;
    }
    __syncthreads();
    if (t < 64) {
      float mx = redA[0][t];
#pragma unroll
      for (int g = 1; g < 16; ++g) mx = fmaxf(mx, redA[g][t]);
      float mn = fmaxf(mrow[t], mx * 0.125f);
      scl[t] = __expf(mrow[t] - mn);
      mrow[t] = mn;
    }
    __syncthreads();
    float4 vld[4];
#pragma unroll
    for (int i = 0; i < 4; ++i)
      vld[i] = *(const float4*)&Vb[(size_t)(s0 + lj) * HD + lk4 + 4 * i];
    float psum[4] = {};
#pragma unroll
    for (int i = 0; i < 4; ++i) {
#pragma unroll
      for (int j = 0; j < 4; ++j) {
        float e = __expf(sacc[i][j] * 0.125f - mrow[q4 + i]);
        Ps[j4g + j][q4 + i] = e;
        psum[i] += e;
      }
      redB[t >> 4][q4 + i] = psum[i];
    }
#pragma unroll
    for (int i = 0; i < 4; ++i)
      *(float4*)&KV[lj][lk4 + 4 * i] = vld[i];
    __syncthreads();
    if (t < 64) {
      float ts = redB[0][t];
#pragma unroll
      for (int g = 1; g < 16; ++g) ts += redB[g][t];
      lrow[t] = lrow[t] * scl[t] + ts;
    }
#pragma unroll
    for (int i = 0; i < 4; ++i) {
      float fsc = scl[q4 + i];
      acc[i][0] *= fsc; acc[i][1] *= fsc; acc[i][2] *= fsc; acc[i][3] *= fsc;
    }
#pragma unroll 16
    for (int j = 0; j < 64; ++j) {
      float4 a = *(const float4*)&Ps[j][q4];
      float4 b = *(const float4*)&KV[j][d4];
      acc[0][0] += a.x*b.x; acc[0][1] += a.x*b.y; acc[0][2] += a.x*b.z; acc[0][3] += a.x*b.w;
      acc[1][0] += a.y*b.x; acc[1][1] += a.y*b.y; acc[1][2] += a.y*b.z; acc[1][3] += a.y*b.w;
      acc[2][0] += a.z*b.x; acc[2][1] += a.z*b.y; acc[2][2] += a.z*b.z; acc[2][3] += a.z*b.w;
      acc[3][0] += a.w*b.x; acc[3][1] += a.w*b.y; acc[3][2] += a.w*b.z; acc[3][3] += a.w*b.w;
    }
  }
  const size_t pb = ((size_t)bh * NSPLIT + sp) * QPAD;
#pragma unroll
  for (int i = 0; i < 4; ++i) {
    int q = q4 + i;
    if (q < UU) {
#pragma unroll
      for (int j = 0; j < 4; ++j)
        pacc[(pb + q) * HD + d4 + j] = acc[i][j];
    }
  }
  if (t < UU) { pm[pb + t] = mrow[t]; pl[pb + t] = lrow[t]; }
}

__global__ __launch_bounds__(256) void attn_combine(
    const float* __restrict__ pacc, const float* __restrict__ pm,
    const float* __restrict__ pl, float* __restrict__ ctx)
{
  const int t  = threadIdx.x;
  const int bh = blockIdx.x;
  const int d = t & 63, qg = t >> 6;
  for (int q = qg; q < UU; q += 4) {
    float m0 = pm[((size_t)bh * NSPLIT + 0) * QPAD + q];
    float m1 = pm[((size_t)bh * NSPLIT + 1) * QPAD + q];
    float m2 = pm[((size_t)bh * NSPLIT + 2) * QPAD + q];
    float m3 = pm[((size_t)bh * NSPLIT + 3) * QPAD + q];
    float ms = fmaxf(fmaxf(m0, m1), fmaxf(m2, m3));
    float w0 = __expf(m0 - ms), w1 = __expf(m1 - ms), w2 = __expf(m2 - ms), w3 = __expf(m3 - ms);
    float l = w0 * pl[((size_t)bh * NSPLIT + 0) * QPAD + q]
            + w1 * pl[((size_t)bh * NSPLIT + 1) * QPAD + q]
            + w2 * pl[((size_t)bh * NSPLIT + 2) * QPAD + q]
            + w3 * pl[((size_t)bh * NSPLIT + 3) * QPAD + q];
    float c = w0 * pacc[(((size_t)bh * NSPLIT + 0) * QPAD + q) * HD + d]
            + w1 * pacc[(((size_t)bh * NSPLIT + 1) * QPAD + q) * HD + d]
            + w2 * pacc[(((size_t)bh * NSPLIT + 2) * QPAD + q) * HD + d]
            + w3 * pacc[(((size_t)bh * NSPLIT + 3) * QPAD + q) * HD + d];
    ctx[((size_t)bh * UU + q) * HD + d] = c / l;
  }
}

__global__ void base_kernel(const float* __restrict__ Vmean, const float* __restrict__ Wo,
                            const float* __restrict__ bo, float* __restrict__ base)
{
  const int c = blockIdx.x * 256 + threadIdx.x;
  float acc[BB] = {};
  for (int k = 0; k < DD; ++k) {
    float w = Wo[(size_t)k * DD + c];
#pragma unroll
    for (int b = 0; b < BB; ++b) acc[b] += Vmean[b * DD + k] * w;
  }
#pragma unroll
  for (int b = 0; b < BB; ++b) base[b * DD + c] = acc[b] + bo[c];
}

__global__ void fill_kernel(const float* __restrict__ base, float* __restrict__ out)
{
  size_t i = (size_t)blockIdx.x * 256 + threadIdx.x;
  float4 bv = ((const float4*)base)[(i >> 19) * 256 + (i & 255)];
  ((float4*)out)[i] = bv;
}

__global__ __launch_bounds__(256) void scatter_kernel(
    const float* __restrict__ ctx, const float* __restrict__ Vmean,
    const int* __restrict__ topi, const float* __restrict__ Wo,
    float* __restrict__ out)
{
  __shared__ float delta[64];
  const int t  = threadIdx.x;
  const int bh = blockIdx.x;
  const int u  = blockIdx.y;
  const int b = bh >> 4, h = bh & 15;
  const int s = topi[bh * UU + u];
  if (t < 64) delta[t] = ctx[((size_t)bh * UU + u) * HD + t] - Vmean[bh * HD + t];
  __syncthreads();
  float* orow = out + ((size_t)b * SS + s) * DD;
#pragma unroll
  for (int j = 0; j < 4; ++j) {
    int c = t + j * 256;
    float acc = 0.f;
#pragma unroll 8
    for (int d = 0; d < 64; ++d) acc += delta[d] * Wo[(size_t)(h * HD + d) * DD + c];
    atomicAdd(&orow[c], acc);
  }
}

extern "C" void kernel_launch(void* const* d_in, const int* in_sizes, int n_in,
                              void* d_out, int out_size, void* d_ws, size_t ws_size,
                              hipStream_t stream) {
  const float* x  = (const float*)d_in[0];
  const float* Wq = (const float*)d_in[1];
  const float* bq = (const float*)d_in[2];
  const float* Wk = (const float*)d_in[3];
  const float* bk = (const float*)d_in[4];
  const float* Wv = (const float*)d_in[5];
  const float* bv = (const float*)d_in[6];
  const float* Wo = (const float*)d_in[7];
  const float* bo = (const float*)d_in[8];
  const int* sidx = (const int*)d_in[9];
  float* out = (float*)d_out;

  float* f     = (float*)d_ws;
  float* K     = f;                          // QSZ
  float* V     = f + (size_t)QSZ;            // QSZ
  float* Kmean = f + (size_t)2 * QSZ;
  float* Vmean = Kmean + BH * HD;
  float* Mbuf  = Vmean + BH * HD;
  float* base  = Mbuf + (size_t)BH * SS;
  float* ctx   = base + BB * DD;
  float* pacc  = ctx + (size_t)BH * UU * HD;
  float* pm    = pacc + (size_t)BH * NSPLIT * QPAD * HD;
  float* pl    = pm + (size_t)BH * NSPLIT * QPAD;
  int*   topi  = (int*)(pl + (size_t)BH * NSPLIT * QPAD);
  int*   uidx  = topi + 4096;                   // 2048 + pad
  int*   ucount= uidx + 4096;
  ushortT* usp = (ushortT*)(ucount + 64);
  ushortT* WqhT = usp;                          // DD*DD each
  ushortT* WqlT = WqhT + (size_t)DD * DD;
  ushortT* WkhT = WqlT + (size_t)DD * DD;
  ushortT* WklT = WkhT + (size_t)DD * DD;
  ushortT* WvhT = WklT + (size_t)DD * DD;
  ushortT* WvlT = WvhT + (size_t)DD * DD;
  ushortT* xh   = WvlT + (size_t)DD * DD;       // NROWS*DD
  ushortT* xl   = xh + (size_t)NROWS * DD;
  ushortT* Qhg  = xl + (size_t)NROWS * DD;      // QSZ
  ushortT* Qlg  = Qhg + (size_t)QSZ;
  ushortT* Khg  = Qlg + (size_t)QSZ;
  ushortT* Klg  = Khg + (size_t)QSZ;

  split_x<<<NROWS * DD / (256 * 8), 256, 0, stream>>>(x, xh, xl);
  dim3 gs(16, 16);
  splitT_kernel<<<gs, 256, 0, stream>>>(Wq, WqhT, WqlT);
  splitT_kernel<<<gs, 256, 0, stream>>>(Wk, WkhT, WklT);
  splitT_kernel<<<gs, 256, 0, stream>>>(Wv, WvhT, WvlT);
  dedupe_kernel<<<1, 256, 0, stream>>>(sidx, uidx, ucount);
  gemm_mfma<true, false><<<512, 256, 0, stream>>>(xh, xl, WqhT, WqlT, bq, nullptr, Qhg, Qlg);
  gemm_mfma<true, true ><<<512, 256, 0, stream>>>(xh, xl, WkhT, WklT, bk, K, Khg, Klg);
  gemm_mfma<false, true><<<512, 256, 0, stream>>>(xh, xl, WvhT, WvlT, bv, V, nullptr, nullptr);
  means_kernel<<<BH, 256, 0, stream>>>(K, V, sidx, Kmean, Vmean);
  m_mfma<<<1024, 256, 0, stream>>>(Qhg, Qlg, Khg, Klg, uidx, ucount, Kmean, Mbuf);
  topk_kernel<<<BH, 256, 0, stream>>>(Mbuf, topi);
  attn_flash<<<dim3(BH, NSPLIT), 256, 0, stream>>>(Qhg, Qlg, K, V, topi, pacc, pm, pl);
  attn_combine<<<BH, 256, 0, stream>>>(pacc, pm, pl, ctx);
  base_kernel<<<DD / 256, 256, 0, stream>>>(Vmean, Wo, bo, base);
  fill_kernel<<<(NROWS * DD / 4) / 256, 256, 0, stream>>>(base, out);
  scatter_kernel<<<dim3(BH, UU), 256, 0, stream>>>(ctx, Vmean, topi, Wo, out);
}